// Round 1
// baseline (11899.971 us; speedup 1.0000x reference)
//
#include <hip/hip_runtime.h>

#define R_TOT  8192      // B*S
#define DIM    768       // D
#define FDICT  32768
#define TOPK   128
#define LN_EPS 1e-5f

// ---------------- K1: encoder GEMM fp32: Z[r,f] = dot(X[r,:], W[f,:]) + b[f] ----
// X [R,768] row-major, W [32768,768] row-major (A*B^T shape), Z [R,32768]
// 128x128 tile, 256 threads, 8x8 per thread (split as 4x4 quadrants), BK=16
__global__ __launch_bounds__(256) void enc_gemm(
    const float* __restrict__ X, const float* __restrict__ W,
    const float* __restrict__ benc, float* __restrict__ Z)
{
    __shared__ __align__(16) float As[16][128];
    __shared__ __align__(16) float Bs[16][128];
    const int t  = threadIdx.x;
    const int ty = t >> 4;        // 0..15
    const int tx = t & 15;        // 0..15
    const long bm = (long)blockIdx.y * 128;
    const long bn = (long)blockIdx.x * 128;

    float acc[8][8];
#pragma unroll
    for (int i = 0; i < 8; ++i)
#pragma unroll
        for (int j = 0; j < 8; ++j) acc[i][j] = 0.f;

    for (int k0 = 0; k0 < DIM; k0 += 16) {
#pragma unroll
        for (int i = 0; i < 2; ++i) {
            const int id = t + i * 256;      // 0..511
            const int rr = id >> 2;          // tile row 0..127
            const int cc = (id & 3) << 2;    // k offset 0,4,8,12
            const float4 av = *(const float4*)(X + (bm + rr) * DIM + k0 + cc);
            As[cc + 0][rr] = av.x; As[cc + 1][rr] = av.y;
            As[cc + 2][rr] = av.z; As[cc + 3][rr] = av.w;
            const float4 bv = *(const float4*)(W + (bn + rr) * DIM + k0 + cc);
            Bs[cc + 0][rr] = bv.x; Bs[cc + 1][rr] = bv.y;
            Bs[cc + 2][rr] = bv.z; Bs[cc + 3][rr] = bv.w;
        }
        __syncthreads();
#pragma unroll
        for (int kk = 0; kk < 16; ++kk) {
            const float4* Ar = (const float4*)(&As[kk][0]);
            const float4* Br = (const float4*)(&Bs[kk][0]);
            const float4 va0 = Ar[ty], va1 = Ar[16 + ty];
            const float4 vb0 = Br[tx], vb1 = Br[16 + tx];
            const float ar[8] = {va0.x, va0.y, va0.z, va0.w,
                                 va1.x, va1.y, va1.z, va1.w};
            const float br[8] = {vb0.x, vb0.y, vb0.z, vb0.w,
                                 vb1.x, vb1.y, vb1.z, vb1.w};
#pragma unroll
            for (int i = 0; i < 8; ++i)
#pragma unroll
                for (int j = 0; j < 8; ++j)
                    acc[i][j] = fmaf(ar[i], br[j], acc[i][j]);
        }
        __syncthreads();
    }

    const float4 bb0 = *(const float4*)(benc + bn + tx * 4);
    const float4 bb1 = *(const float4*)(benc + bn + 64 + tx * 4);
#pragma unroll
    for (int i = 0; i < 8; ++i) {
        const long row = bm + (i < 4 ? ty * 4 + i : 64 + ty * 4 + (i - 4));
        float4 v0, v1;
        v0.x = acc[i][0] + bb0.x; v0.y = acc[i][1] + bb0.y;
        v0.z = acc[i][2] + bb0.z; v0.w = acc[i][3] + bb0.w;
        v1.x = acc[i][4] + bb1.x; v1.y = acc[i][5] + bb1.y;
        v1.z = acc[i][6] + bb1.z; v1.w = acc[i][7] + bb1.w;
        *(float4*)(Z + row * FDICT + bn + tx * 4)      = v0;
        *(float4*)(Z + row * FDICT + bn + 64 + tx * 4) = v1;
    }
}

// ---------------- K2: fused stats + LN + exact top-128 selection ----------------
// One block per row. Row staged in LDS; 3-pass radix histogram on float bits
// (monotone for values >= 0, guaranteed by relu). jax tie semantics: value
// desc, index asc.
__global__ __launch_bounds__(1024) void topk_select(
    const float* __restrict__ Z, const float* __restrict__ gamma,
    const float* __restrict__ beta, int* __restrict__ sel_idx,
    float* __restrict__ sel_val)
{
    __shared__ __align__(16) float zs[FDICT];   // 128 KB (aliased as uint)
    __shared__ unsigned hist[2048];             // 8 KB
    __shared__ float redf[32];
    __shared__ unsigned su[8];
    __shared__ float sf[2];
    __shared__ int ties[1024];

    unsigned* zu = (unsigned*)zs;
    const int t = threadIdx.x;
    const long r = blockIdx.x;

    // load row + partial sums
    float sum = 0.f, sumsq = 0.f;
    const float4* Z4 = (const float4*)(Z + r * FDICT);
    float4* zs4 = (float4*)zs;
    for (int i = t; i < FDICT / 4; i += 1024) {
        const float4 v = Z4[i];
        zs4[i] = v;
        sum   += v.x + v.y + v.z + v.w;
        sumsq += v.x * v.x + v.y * v.y + v.z * v.z + v.w * v.w;
    }
#pragma unroll
    for (int o = 32; o > 0; o >>= 1) {
        sum   += __shfl_down(sum, o, 64);
        sumsq += __shfl_down(sumsq, o, 64);
    }
    if ((t & 63) == 0) { redf[t >> 6] = sum; redf[16 + (t >> 6)] = sumsq; }
    for (int i = t; i < 2048; i += 1024) hist[i] = 0;
    __syncthreads();
    if (t == 0) {
        float s = 0.f, sq = 0.f;
        for (int w = 0; w < 16; ++w) { s += redf[w]; sq += redf[16 + w]; }
        const float mu = s / (float)FDICT;
        float var = sq / (float)FDICT - mu * mu;
        if (var < 0.f) var = 0.f;
        sf[0] = mu;
        sf[1] = 1.f / sqrtf(var + LN_EPS);
        su[6] = 0; su[7] = 0;
    }
    __syncthreads();
    const float mu = sf[0], sinv = sf[1];

    // normalize in place (as monotone uint) + pass-1 histogram (bits 30:20)
    unsigned zloc = 0;
    for (int i = t; i < FDICT; i += 1024) {
        float a = fmaf((zs[i] - mu) * sinv, gamma[i], beta[i]);
        a = fmaxf(a, 0.f);
        const unsigned u = __float_as_uint(a);
        zu[i] = u;
        if (u == 0u) ++zloc;                    // avoid atomic storm on bin 0
        else atomicAdd(&hist[u >> 20], 1u);
    }
    if (zloc) atomicAdd(&hist[0], zloc);
    __syncthreads();
    if (t == 0) {
        unsigned c = 0; int b = 2047;
        for (; b >= 0; --b) { const unsigned h = hist[b]; if (c + h >= TOPK) break; c += h; }
        su[0] = (unsigned)b; su[1] = c;
    }
    __syncthreads();

    // pass 2: bits 19:9 within boundary bin
    const unsigned b1 = su[0], c1 = su[1];
    for (int i = t; i < 2048; i += 1024) hist[i] = 0;
    __syncthreads();
    for (int i = t; i < FDICT; i += 1024) {
        const unsigned u = zu[i];
        if ((u >> 20) == b1) atomicAdd(&hist[(u >> 9) & 0x7FFu], 1u);
    }
    __syncthreads();
    if (t == 0) {
        unsigned c = c1; int b = 2047;
        for (; b >= 0; --b) { const unsigned h = hist[b]; if (c + h >= TOPK) break; c += h; }
        su[2] = (unsigned)b; su[3] = c;
    }
    __syncthreads();

    // pass 3: bits 8:0
    const unsigned b2 = su[2], c2 = su[3];
    const unsigned pfx = (b1 << 11) | b2;
    for (int i = t; i < 512; i += 1024) hist[i] = 0;
    __syncthreads();
    for (int i = t; i < FDICT; i += 1024) {
        const unsigned u = zu[i];
        if ((u >> 9) == pfx) atomicAdd(&hist[u & 0x1FFu], 1u);
    }
    __syncthreads();
    if (t == 0) {
        unsigned c = c2; int b = 511;
        for (; b >= 0; --b) { const unsigned h = hist[b]; if (c + h >= TOPK) break; c += h; }
        su[4] = (pfx << 9) | (unsigned)b;   // T = exact bits of 128th largest
        su[5] = c;                          // count(u > T)  (< 128)
    }
    __syncthreads();
    const unsigned T = su[4], cAbove = su[5];

    // compact: all u > T, plus (128 - cAbove) smallest-index ties (u == T)
    for (int i = t; i < FDICT; i += 1024) {
        const unsigned u = zu[i];
        if (u > T) {
            const unsigned s = atomicAdd(&su[6], 1u);
            sel_idx[r * TOPK + s] = i;
            sel_val[r * TOPK + s] = __uint_as_float(u);
        } else if (u == T) {
            const unsigned s = atomicAdd(&su[7], 1u);
            if (s < 1024) ties[s] = i;
        }
    }
    __syncthreads();
    if (t == 0) {
        const int need = TOPK - (int)cAbove;
        int e = (int)su[7]; if (e > 1024) e = 1024;
        for (int a = 0; a < need; ++a) {
            int mi = a;
            for (int b = a + 1; b < e; ++b) if (ties[b] < ties[mi]) mi = b;
            const int tmp = ties[a]; ties[a] = ties[mi]; ties[mi] = tmp;
            sel_idx[r * TOPK + cAbove + a] = ties[a];
            sel_val[r * TOPK + cAbove + a] = __uint_as_float(T);
        }
    }
}

// ---------------- K3: transpose W_dec [768][32768] -> WdT [32768][768] ----------
__global__ __launch_bounds__(256) void transposeWd(
    const float* __restrict__ Wd, float* __restrict__ WdT)
{
    __shared__ float tile[32][33];
    const int fx = blockIdx.x * 32;
    const int dy = blockIdx.y * 32;
    const int tx = threadIdx.x & 31;
    const int ty = threadIdx.x >> 5;            // 0..7
    for (int i = ty; i < 32; i += 8)
        tile[i][tx] = Wd[(size_t)(dy + i) * FDICT + fx + tx];
    __syncthreads();
    for (int i = ty; i < 32; i += 8)
        WdT[(size_t)(fx + i) * DIM + dy + tx] = tile[tx][i];
}

// ---------------- K4: sparse decode: out[r,:] = b_dec + sum_j val_j * WdT[idx_j,:]
__global__ __launch_bounds__(256) void decode(
    const int* __restrict__ sel_idx, const float* __restrict__ sel_val,
    const float* __restrict__ WdT, const float* __restrict__ bdec,
    float* __restrict__ out)
{
    __shared__ int   sidx[TOPK];
    __shared__ float sval[TOPK];
    const int t = threadIdx.x;
    const long r = blockIdx.x;
    if (t < TOPK) { sidx[t] = sel_idx[r * TOPK + t]; sval[t] = sel_val[r * TOPK + t]; }
    __syncthreads();
    float a0 = bdec[t], a1 = bdec[256 + t], a2 = bdec[512 + t];
    for (int j = 0; j < TOPK; ++j) {
        const float* w = WdT + (size_t)sidx[j] * DIM;
        const float v = sval[j];
        a0 = fmaf(v, w[t], a0);
        a1 = fmaf(v, w[256 + t], a1);
        a2 = fmaf(v, w[512 + t], a2);
    }
    out[r * DIM + t]       = a0;
    out[r * DIM + 256 + t] = a1;
    out[r * DIM + 512 + t] = a2;
}

// ---------------- K5: finalize features: zero row + scatter selected ------------
__global__ __launch_bounds__(1024) void featfill(
    const int* __restrict__ sel_idx, const float* __restrict__ sel_val,
    float* __restrict__ feat)
{
    const int t = threadIdx.x;
    const long r = blockIdx.x;
    float4 z4; z4.x = 0.f; z4.y = 0.f; z4.z = 0.f; z4.w = 0.f;
    float4* row4 = (float4*)(feat + r * FDICT);
    for (int i = t; i < FDICT / 4; i += 1024) row4[i] = z4;
    __syncthreads();
    if (t < TOPK)
        feat[r * FDICT + sel_idx[r * TOPK + t]] = sel_val[r * TOPK + t];
}

extern "C" void kernel_launch(void* const* d_in, const int* in_sizes, int n_in,
                              void* d_out, int out_size, void* d_ws, size_t ws_size,
                              hipStream_t stream)
{
    const float* x     = (const float*)d_in[0];
    const float* Wenc  = (const float*)d_in[1];
    const float* benc  = (const float*)d_in[2];
    const float* gamma = (const float*)d_in[3];
    const float* beta  = (const float*)d_in[4];
    const float* Wdec  = (const float*)d_in[5];
    const float* bdec  = (const float*)d_in[6];

    float* out  = (float*)d_out;                      // [8192*768]
    float* feat = out + (size_t)R_TOT * DIM;          // [8192*32768]
    int*   sidx = (int*)d_ws;                         // 8192*128 ints   (4 MB)
    float* sval = (float*)d_ws + (size_t)R_TOT * TOPK;// 8192*128 floats (4 MB)

    // K1: z -> feat region (scratch use of the features output)
    enc_gemm<<<dim3(FDICT / 128, R_TOT / 128), 256, 0, stream>>>(x, Wenc, benc, feat);
    // K2: exact top-128 per row -> compact lists in ws
    topk_select<<<R_TOT, 1024, 0, stream>>>(feat, gamma, beta, sidx, sval);
    // K3: W_dec^T into the (now dead) front of the feat region
    transposeWd<<<dim3(FDICT / 32, DIM / 32), 256, 0, stream>>>(Wdec, feat);
    // K4: sparse decode -> reconstruction output
    decode<<<R_TOT, 256, 0, stream>>>(sidx, sval, feat, bdec, out);
    // K5: finalize features (zero + scatter)
    featfill<<<R_TOT, 1024, 0, stream>>>(sidx, sval, feat);
}

// Round 2
// 6552.801 us; speedup vs baseline: 1.8160x; 1.8160x over previous
//
#include <hip/hip_runtime.h>

#define R_TOT  8192      // B*S
#define DIM    768       // D
#define FDICT  32768
#define TOPK   128
#define LN_EPS 1e-5f

// ---------------- K1: encoder GEMM fp32: Z[r,f] = dot(X[r,:], W[f,:]) + b[f] ----
__global__ __launch_bounds__(256) void enc_gemm(
    const float* __restrict__ X, const float* __restrict__ W,
    const float* __restrict__ benc, float* __restrict__ Z)
{
    __shared__ __align__(16) float As[16][128];
    __shared__ __align__(16) float Bs[16][128];
    const int t  = threadIdx.x;
    const int ty = t >> 4;        // 0..15
    const int tx = t & 15;        // 0..15
    const long bm = (long)blockIdx.y * 128;
    const long bn = (long)blockIdx.x * 128;

    float acc[8][8];
#pragma unroll
    for (int i = 0; i < 8; ++i)
#pragma unroll
        for (int j = 0; j < 8; ++j) acc[i][j] = 0.f;

    for (int k0 = 0; k0 < DIM; k0 += 16) {
#pragma unroll
        for (int i = 0; i < 2; ++i) {
            const int id = t + i * 256;      // 0..511
            const int rr = id >> 2;          // tile row 0..127
            const int cc = (id & 3) << 2;    // k offset 0,4,8,12
            const float4 av = *(const float4*)(X + (bm + rr) * DIM + k0 + cc);
            As[cc + 0][rr] = av.x; As[cc + 1][rr] = av.y;
            As[cc + 2][rr] = av.z; As[cc + 3][rr] = av.w;
            const float4 bv = *(const float4*)(W + (bn + rr) * DIM + k0 + cc);
            Bs[cc + 0][rr] = bv.x; Bs[cc + 1][rr] = bv.y;
            Bs[cc + 2][rr] = bv.z; Bs[cc + 3][rr] = bv.w;
        }
        __syncthreads();
#pragma unroll
        for (int kk = 0; kk < 16; ++kk) {
            const float4* Ar = (const float4*)(&As[kk][0]);
            const float4* Br = (const float4*)(&Bs[kk][0]);
            const float4 va0 = Ar[ty], va1 = Ar[16 + ty];
            const float4 vb0 = Br[tx], vb1 = Br[16 + tx];
            const float ar[8] = {va0.x, va0.y, va0.z, va0.w,
                                 va1.x, va1.y, va1.z, va1.w};
            const float br[8] = {vb0.x, vb0.y, vb0.z, vb0.w,
                                 vb1.x, vb1.y, vb1.z, vb1.w};
#pragma unroll
            for (int i = 0; i < 8; ++i)
#pragma unroll
                for (int j = 0; j < 8; ++j)
                    acc[i][j] = fmaf(ar[i], br[j], acc[i][j]);
        }
        __syncthreads();
    }

    const float4 bb0 = *(const float4*)(benc + bn + tx * 4);
    const float4 bb1 = *(const float4*)(benc + bn + 64 + tx * 4);
#pragma unroll
    for (int i = 0; i < 8; ++i) {
        const long row = bm + (i < 4 ? ty * 4 + i : 64 + ty * 4 + (i - 4));
        float4 v0, v1;
        v0.x = acc[i][0] + bb0.x; v0.y = acc[i][1] + bb0.y;
        v0.z = acc[i][2] + bb0.z; v0.w = acc[i][3] + bb0.w;
        v1.x = acc[i][4] + bb1.x; v1.y = acc[i][5] + bb1.y;
        v1.z = acc[i][6] + bb1.z; v1.w = acc[i][7] + bb1.w;
        *(float4*)(Z + row * FDICT + bn + tx * 4)      = v0;
        *(float4*)(Z + row * FDICT + bn + 64 + tx * 4) = v1;
    }
}

// ---------------- K2: fused stats + LN + exact top-128 (register-resident) ------
// One block (1024 thr) per row; 32 values/thread in VGPRs. Stats via shfl.
// 4-pass byte radix over monotone uint bits, per-wave bank-padded histograms.
// Tie-break = jax semantics: value desc, index asc.
__global__ __launch_bounds__(1024) void topk_select(
    const float* __restrict__ Z, const float* __restrict__ gamma,
    const float* __restrict__ beta, int* __restrict__ sel_idx,
    float* __restrict__ sel_val)
{
    __shared__ unsigned hist[16 * 257];   // per-wave copies, +1 pad (bank stagger)
    __shared__ unsigned finalh[256];
    __shared__ unsigned superh[16];
    __shared__ float    redf[32];
    __shared__ float    sf[2];
    __shared__ unsigned sb[2];
    __shared__ unsigned scomp[2];
    __shared__ int      ties[1024];

    const int t = threadIdx.x;
    const int w = t >> 6;
    const long r = blockIdx.x;

    // ---- load row into registers + partial stats ----
    unsigned u[32];
    float sum = 0.f, sumsq = 0.f;
    const float4* Z4 = (const float4*)(Z + r * FDICT);
#pragma unroll
    for (int q = 0; q < 8; ++q) {
        const float4 x4 = Z4[q * 1024 + t];
        u[4*q+0] = __float_as_uint(x4.x); u[4*q+1] = __float_as_uint(x4.y);
        u[4*q+2] = __float_as_uint(x4.z); u[4*q+3] = __float_as_uint(x4.w);
        sum   += x4.x + x4.y + x4.z + x4.w;
        sumsq += x4.x*x4.x + x4.y*x4.y + x4.z*x4.z + x4.w*x4.w;
    }
#pragma unroll
    for (int o = 32; o > 0; o >>= 1) {
        sum   += __shfl_down(sum, o, 64);
        sumsq += __shfl_down(sumsq, o, 64);
    }
    if ((t & 63) == 0) { redf[w] = sum; redf[16 + w] = sumsq; }
    __syncthreads();
    if (t == 0) {
        float s = 0.f, sq = 0.f;
        for (int i = 0; i < 16; ++i) { s += redf[i]; sq += redf[16 + i]; }
        const float mu = s / (float)FDICT;
        float var = sq / (float)FDICT - mu * mu;
        if (var < 0.f) var = 0.f;
        sf[0] = mu; sf[1] = 1.f / sqrtf(var + LN_EPS);
        scomp[0] = 0; scomp[1] = 0;
    }
    __syncthreads();
    const float mu = sf[0], sinv = sf[1];

    // ---- normalize in registers: a = relu((z-mu)*sinv*g + b), keep uint bits ----
#pragma unroll
    for (int q = 0; q < 8; ++q) {
        const float4 g4 = *(const float4*)(gamma + (size_t)(q * 1024 + t) * 4);
        const float4 b4 = *(const float4*)(beta  + (size_t)(q * 1024 + t) * 4);
        u[4*q+0] = __float_as_uint(fmaxf(fmaf((__uint_as_float(u[4*q+0]) - mu) * sinv, g4.x, b4.x), 0.f));
        u[4*q+1] = __float_as_uint(fmaxf(fmaf((__uint_as_float(u[4*q+1]) - mu) * sinv, g4.y, b4.y), 0.f));
        u[4*q+2] = __float_as_uint(fmaxf(fmaf((__uint_as_float(u[4*q+2]) - mu) * sinv, g4.z, b4.z), 0.f));
        u[4*q+3] = __float_as_uint(fmaxf(fmaf((__uint_as_float(u[4*q+3]) - mu) * sinv, g4.w, b4.w), 0.f));
    }

    // ---- 4-pass byte radix: find exact bits T of the 128th largest ----
    unsigned pfx = 0;      // value of bits [31 : sh+8]
    unsigned cab = 0;      // count(u with (u>>sh) > current path), < 128
    unsigned* h = &hist[w * 257];
#pragma unroll 1
    for (int p = 0; p < 4; ++p) {
        const int sh = 24 - 8 * p;
        for (int i = t; i < 16 * 257; i += 1024) hist[i] = 0;
        __syncthreads();
        if (p == 0) {
            unsigned zc = 0;
#pragma unroll
            for (int i = 0; i < 32; ++i) {
                const unsigned uu = u[i];
                if (uu == 0u) ++zc; else atomicAdd(&h[uu >> 24], 1u);
            }
            if (zc) atomicAdd(&h[0], zc);
        } else {
#pragma unroll
            for (int i = 0; i < 32; ++i) {
                const unsigned uu = u[i];
                if ((uu >> (sh + 8)) == pfx) atomicAdd(&h[(uu >> sh) & 255u], 1u);
            }
        }
        __syncthreads();
        if (t < 256) {
            unsigned s = 0;
#pragma unroll
            for (int c = 0; c < 16; ++c) s += hist[c * 257 + t];
            finalh[t] = s;
        }
        __syncthreads();
        if (t < 16) {
            unsigned s = 0;
            for (int b = 0; b < 16; ++b) s += finalh[t * 16 + b];
            superh[t] = s;
        }
        __syncthreads();
        if (t == 0) {
            const unsigned need = TOPK - cab;   // >=1; sub-hist total >= need
            unsigned c = 0; int ss = 15;
            for (;;) { const unsigned hs = superh[ss]; if (c + hs >= need) break; c += hs; --ss; }
            int b = ss * 16 + 15;
            for (;;) { const unsigned hb = finalh[b]; if (c + hb >= need) break; c += hb; --b; }
            sb[0] = (unsigned)b; sb[1] = cab + c;
        }
        __syncthreads();
        pfx = (pfx << 8) | sb[0];
        cab = sb[1];
    }
    const unsigned T = pfx, cAbove = cab;

    // ---- compact: all u > T, plus (128 - cAbove) smallest-index ties (u == T) ---
#pragma unroll
    for (int i = 0; i < 32; ++i) {
        const unsigned uu = u[i];
        const int idx = (i >> 2) * 4096 + t * 4 + (i & 3);
        if (uu > T) {
            const unsigned s = atomicAdd(&scomp[0], 1u);
            sel_idx[r * TOPK + s] = idx;
            sel_val[r * TOPK + s] = __uint_as_float(uu);
        } else if (uu == T) {
            const unsigned s = atomicAdd(&scomp[1], 1u);
            if (s < 1024) ties[s] = idx;
        }
    }
    __syncthreads();
    if (t == 0) {
        const int need = TOPK - (int)cAbove;
        int e = (int)scomp[1]; if (e > 1024) e = 1024;
        for (int a = 0; a < need; ++a) {
            int mi = a;
            for (int b2 = a + 1; b2 < e; ++b2) if (ties[b2] < ties[mi]) mi = b2;
            const int tmp = ties[a]; ties[a] = ties[mi]; ties[mi] = tmp;
            sel_idx[r * TOPK + cAbove + a] = ties[a];
            sel_val[r * TOPK + cAbove + a] = __uint_as_float(T);
        }
    }
}

// ---------------- K3: transpose W_dec [768][32768] -> WdT [32768][768] ----------
__global__ __launch_bounds__(256) void transposeWd(
    const float* __restrict__ Wd, float* __restrict__ WdT)
{
    __shared__ float tile[32][33];
    const int fx = blockIdx.x * 32;
    const int dy = blockIdx.y * 32;
    const int tx = threadIdx.x & 31;
    const int ty = threadIdx.x >> 5;            // 0..7
    for (int i = ty; i < 32; i += 8)
        tile[i][tx] = Wd[(size_t)(dy + i) * FDICT + fx + tx];
    __syncthreads();
    for (int i = ty; i < 32; i += 8)
        WdT[(size_t)(fx + i) * DIM + dy + tx] = tile[tx][i];
}

// ---------------- K4: sparse decode: out[r,:] = b_dec + sum_j val_j * WdT[idx_j,:]
__global__ __launch_bounds__(256) void decode(
    const int* __restrict__ sel_idx, const float* __restrict__ sel_val,
    const float* __restrict__ WdT, const float* __restrict__ bdec,
    float* __restrict__ out)
{
    __shared__ int   sidx[TOPK];
    __shared__ float sval[TOPK];
    const int t = threadIdx.x;
    const long r = blockIdx.x;
    if (t < TOPK) { sidx[t] = sel_idx[r * TOPK + t]; sval[t] = sel_val[r * TOPK + t]; }
    __syncthreads();
    float a0 = bdec[t], a1 = bdec[256 + t], a2 = bdec[512 + t];
    for (int j = 0; j < TOPK; ++j) {
        const float* w = WdT + (size_t)sidx[j] * DIM;
        const float v = sval[j];
        a0 = fmaf(v, w[t], a0);
        a1 = fmaf(v, w[256 + t], a1);
        a2 = fmaf(v, w[512 + t], a2);
    }
    out[r * DIM + t]       = a0;
    out[r * DIM + 256 + t] = a1;
    out[r * DIM + 512 + t] = a2;
}

// ---------------- K5: finalize features: zero row + scatter selected ------------
__global__ __launch_bounds__(1024) void featfill(
    const int* __restrict__ sel_idx, const float* __restrict__ sel_val,
    float* __restrict__ feat)
{
    const int t = threadIdx.x;
    const long r = blockIdx.x;
    float4 z4; z4.x = 0.f; z4.y = 0.f; z4.z = 0.f; z4.w = 0.f;
    float4* row4 = (float4*)(feat + r * FDICT);
    for (int i = t; i < FDICT / 4; i += 1024) row4[i] = z4;
    __syncthreads();
    if (t < TOPK)
        feat[r * FDICT + sel_idx[r * TOPK + t]] = sel_val[r * TOPK + t];
}

extern "C" void kernel_launch(void* const* d_in, const int* in_sizes, int n_in,
                              void* d_out, int out_size, void* d_ws, size_t ws_size,
                              hipStream_t stream)
{
    const float* x     = (const float*)d_in[0];
    const float* Wenc  = (const float*)d_in[1];
    const float* benc  = (const float*)d_in[2];
    const float* gamma = (const float*)d_in[3];
    const float* beta  = (const float*)d_in[4];
    const float* Wdec  = (const float*)d_in[5];
    const float* bdec  = (const float*)d_in[6];

    float* out  = (float*)d_out;                      // [8192*768]
    float* feat = out + (size_t)R_TOT * DIM;          // [8192*32768]
    int*   sidx = (int*)d_ws;                         // 8192*128 ints   (4 MB)
    float* sval = (float*)d_ws + (size_t)R_TOT * TOPK;// 8192*128 floats (4 MB)

    // K1: z -> feat region (scratch use of the features output)
    enc_gemm<<<dim3(FDICT / 128, R_TOT / 128), 256, 0, stream>>>(x, Wenc, benc, feat);
    // K2: exact top-128 per row -> compact lists in ws
    topk_select<<<R_TOT, 1024, 0, stream>>>(feat, gamma, beta, sidx, sval);
    // K3: W_dec^T into the (now dead) front of the feat region
    transposeWd<<<dim3(FDICT / 32, DIM / 32), 256, 0, stream>>>(Wdec, feat);
    // K4: sparse decode -> reconstruction output
    decode<<<R_TOT, 256, 0, stream>>>(sidx, sval, feat, bdec, out);
    // K5: finalize features (zero + scatter)
    featfill<<<R_TOT, 1024, 0, stream>>>(sidx, sval, feat);
}

// Round 3
// 3225.658 us; speedup vs baseline: 3.6892x; 2.0315x over previous
//
#include <hip/hip_runtime.h>
#include <hip/hip_bf16.h>

#define R_TOT  8192      // B*S
#define DIM    768       // D
#define FDICT  32768
#define TOPK   128
#define LN_EPS 1e-5f
#define BAND_M 0.06f
#define BAND_CAP 96

using f32x4  = __attribute__((ext_vector_type(4))) float;
using short8 = __attribute__((ext_vector_type(8))) short;

__device__ inline short f2bf(float f) {
    __hip_bfloat16 h = __float2bfloat16(f);
    return *reinterpret_cast<short*>(&h);
}

// ---------------- K1: encoder GEMM, bf16 MFMA, fp32 accumulate ------------------
// Z[m,n] = sum_k X[m,k]*W[n,k] + b[n].  128x128 tile, BK=64, 4 waves.
// LDS tiles stored in MFMA fragment order (lane-linear ds_read_b128).
__global__ __launch_bounds__(256) void enc_gemm(
    const float* __restrict__ X, const float* __restrict__ W,
    const float* __restrict__ benc, float* __restrict__ Z)
{
    __shared__ __align__(16) unsigned short As[8192];   // 128x64 bf16, frag order
    __shared__ __align__(16) unsigned short Bs[8192];
    const int t = threadIdx.x;
    const int w = t >> 6, l = t & 63;
    const long bm = (long)blockIdx.x * 128;
    const long bn = (long)blockIdx.y * 128;

    // staging: 4 chunks each of A and B; chunk = (row, kgroup of 8 k)
    int coff[4];
    const float* pa[4];
    const float* pb[4];
#pragma unroll
    for (int i = 0; i < 4; ++i) {
        const int c = t + i * 256;           // 0..1023
        const int row = c >> 3, kg = c & 7;
        coff[i] = (row >> 4) * 1024 + (kg >> 2) * 512 + ((row & 15) + ((kg & 3) << 4)) * 8;
        pa[i] = X + (bm + row) * DIM + kg * 8;
        pb[i] = W + (bn + row) * DIM + kg * 8;
    }

    f32x4 acc[4][4];
#pragma unroll
    for (int m = 0; m < 4; ++m)
#pragma unroll
        for (int n = 0; n < 4; ++n) acc[m][n] = (f32x4){0.f, 0.f, 0.f, 0.f};

    const int wm = w >> 1, wn = w & 1;

    for (int kt = 0; kt < DIM / 64; ++kt) {
        float4 ra[4][2], rb[4][2];
#pragma unroll
        for (int i = 0; i < 4; ++i) {
            ra[i][0] = *(const float4*)(pa[i]);
            ra[i][1] = *(const float4*)(pa[i] + 4);
            rb[i][0] = *(const float4*)(pb[i]);
            rb[i][1] = *(const float4*)(pb[i] + 4);
            pa[i] += 64; pb[i] += 64;
        }
#pragma unroll
        for (int i = 0; i < 4; ++i) {
            short8 va, vb;
            va[0] = f2bf(ra[i][0].x); va[1] = f2bf(ra[i][0].y);
            va[2] = f2bf(ra[i][0].z); va[3] = f2bf(ra[i][0].w);
            va[4] = f2bf(ra[i][1].x); va[5] = f2bf(ra[i][1].y);
            va[6] = f2bf(ra[i][1].z); va[7] = f2bf(ra[i][1].w);
            vb[0] = f2bf(rb[i][0].x); vb[1] = f2bf(rb[i][0].y);
            vb[2] = f2bf(rb[i][0].z); vb[3] = f2bf(rb[i][0].w);
            vb[4] = f2bf(rb[i][1].x); vb[5] = f2bf(rb[i][1].y);
            vb[6] = f2bf(rb[i][1].z); vb[7] = f2bf(rb[i][1].w);
            *(short8*)&As[coff[i]] = va;
            *(short8*)&Bs[coff[i]] = vb;
        }
        __syncthreads();
#pragma unroll
        for (int ks = 0; ks < 2; ++ks) {
            short8 af[4], bf_[4];
#pragma unroll
            for (int m = 0; m < 4; ++m)
                af[m] = *(const short8*)&As[(wm * 4 + m) * 1024 + ks * 512 + l * 8];
#pragma unroll
            for (int n = 0; n < 4; ++n)
                bf_[n] = *(const short8*)&Bs[(wn * 4 + n) * 1024 + ks * 512 + l * 8];
#pragma unroll
            for (int m = 0; m < 4; ++m)
#pragma unroll
                for (int n = 0; n < 4; ++n)
                    acc[m][n] = __builtin_amdgcn_mfma_f32_16x16x32_bf16(
                        af[m], bf_[n], acc[m][n], 0, 0, 0);
        }
        __syncthreads();
    }

    // epilogue: D lane mapping col=lane&15 (n), row=(lane>>4)*4+q (m)
    const int lr = l >> 4, lc = l & 15;
#pragma unroll
    for (int n = 0; n < 4; ++n) {
        const long col = bn + wn * 64 + n * 16 + lc;
        const float bias = benc[col];
#pragma unroll
        for (int m = 0; m < 4; ++m) {
            const long rowb = bm + wm * 64 + m * 16 + lr * 4;
#pragma unroll
            for (int q = 0; q < 4; ++q)
                Z[(rowb + q) * FDICT + col] = acc[m][n][q] + bias;
        }
    }
}

// ---------------- K2: stats + LN + approx top-128 + band classification ---------
__global__ __launch_bounds__(1024) void topk_select(
    const float* __restrict__ Z, const float* __restrict__ gamma,
    const float* __restrict__ beta, int* __restrict__ sel_idx,
    float* __restrict__ sel_val, int* __restrict__ band_idx,
    int* __restrict__ cdef, int* __restrict__ nband,
    float* __restrict__ muarr, float* __restrict__ sinvarr)
{
    __shared__ unsigned hist[16 * 257];
    __shared__ unsigned finalh[256];
    __shared__ unsigned superh[16];
    __shared__ float    redf[32];
    __shared__ float    sf[2];
    __shared__ unsigned sb[2];
    __shared__ unsigned scomp[2];

    const int t = threadIdx.x;
    const int w = t >> 6;
    const long r = blockIdx.x;

    unsigned u[32];
    float sum = 0.f, sumsq = 0.f;
    const float4* Z4 = (const float4*)(Z + r * FDICT);
#pragma unroll
    for (int q = 0; q < 8; ++q) {
        const float4 x4 = Z4[q * 1024 + t];
        u[4*q+0] = __float_as_uint(x4.x); u[4*q+1] = __float_as_uint(x4.y);
        u[4*q+2] = __float_as_uint(x4.z); u[4*q+3] = __float_as_uint(x4.w);
        sum   += x4.x + x4.y + x4.z + x4.w;
        sumsq += x4.x*x4.x + x4.y*x4.y + x4.z*x4.z + x4.w*x4.w;
    }
#pragma unroll
    for (int o = 32; o > 0; o >>= 1) {
        sum   += __shfl_down(sum, o, 64);
        sumsq += __shfl_down(sumsq, o, 64);
    }
    if ((t & 63) == 0) { redf[w] = sum; redf[16 + w] = sumsq; }
    __syncthreads();
    if (t == 0) {
        float s = 0.f, sq = 0.f;
        for (int i = 0; i < 16; ++i) { s += redf[i]; sq += redf[16 + i]; }
        const float mu = s / (float)FDICT;
        float var = sq / (float)FDICT - mu * mu;
        if (var < 0.f) var = 0.f;
        sf[0] = mu; sf[1] = 1.f / sqrtf(var + LN_EPS);
        scomp[0] = 0; scomp[1] = 0;
    }
    __syncthreads();
    const float mu = sf[0], sinv = sf[1];

#pragma unroll
    for (int q = 0; q < 8; ++q) {
        const float4 g4 = *(const float4*)(gamma + (size_t)(q * 1024 + t) * 4);
        const float4 b4 = *(const float4*)(beta  + (size_t)(q * 1024 + t) * 4);
        u[4*q+0] = __float_as_uint(fmaxf(fmaf((__uint_as_float(u[4*q+0]) - mu) * sinv, g4.x, b4.x), 0.f));
        u[4*q+1] = __float_as_uint(fmaxf(fmaf((__uint_as_float(u[4*q+1]) - mu) * sinv, g4.y, b4.y), 0.f));
        u[4*q+2] = __float_as_uint(fmaxf(fmaf((__uint_as_float(u[4*q+2]) - mu) * sinv, g4.z, b4.z), 0.f));
        u[4*q+3] = __float_as_uint(fmaxf(fmaf((__uint_as_float(u[4*q+3]) - mu) * sinv, g4.w, b4.w), 0.f));
    }

    // 4-pass byte radix: T = exact bits of 128th largest approx value
    unsigned pfx = 0, cab = 0;
    unsigned* h = &hist[w * 257];
#pragma unroll 1
    for (int p = 0; p < 4; ++p) {
        const int sh = 24 - 8 * p;
        for (int i = t; i < 16 * 257; i += 1024) hist[i] = 0;
        __syncthreads();
        if (p == 0) {
            unsigned zc = 0;
#pragma unroll
            for (int i = 0; i < 32; ++i) {
                const unsigned uu = u[i];
                if (uu == 0u) ++zc; else atomicAdd(&h[uu >> 24], 1u);
            }
            if (zc) atomicAdd(&h[0], zc);
        } else {
#pragma unroll
            for (int i = 0; i < 32; ++i) {
                const unsigned uu = u[i];
                if ((uu >> (sh + 8)) == pfx) atomicAdd(&h[(uu >> sh) & 255u], 1u);
            }
        }
        __syncthreads();
        if (t < 256) {
            unsigned s = 0;
#pragma unroll
            for (int c = 0; c < 16; ++c) s += hist[c * 257 + t];
            finalh[t] = s;
        }
        __syncthreads();
        if (t < 16) {
            unsigned s = 0;
            for (int b = 0; b < 16; ++b) s += finalh[t * 16 + b];
            superh[t] = s;
        }
        __syncthreads();
        if (t == 0) {
            const unsigned need = TOPK - cab;
            unsigned c = 0; int ss = 15;
            for (;;) { const unsigned hs = superh[ss]; if (c + hs >= need) break; c += hs; --ss; }
            int b = ss * 16 + 15;
            for (;;) { const unsigned hb = finalh[b]; if (c + hb >= need) break; c += hb; --b; }
            sb[0] = (unsigned)b; sb[1] = cab + c;
        }
        __syncthreads();
        pfx = (pfx << 8) | sb[0];
        cab = sb[1];
    }

    const float Tf = __uint_as_float(pfx);
    const float thi = Tf + BAND_M, tlo = Tf - BAND_M;

    // classify: definite-in (> T+M) vs band ([T-M, T+M])
#pragma unroll
    for (int i = 0; i < 32; ++i) {
        const float a = __uint_as_float(u[i]);
        const int idx = (i >> 2) * 4096 + t * 4 + (i & 3);
        if (a > thi) {
            const unsigned s = atomicAdd(&scomp[0], 1u);
            sel_idx[r * TOPK + s] = idx;
            sel_val[r * TOPK + s] = a;
        } else if (a >= tlo) {
            const unsigned s = atomicAdd(&scomp[1], 1u);
            if (s < BAND_CAP) band_idx[r * BAND_CAP + s] = idx;
        }
    }
    __syncthreads();
    if (t == 0) {
        cdef[r]  = (int)scomp[0];
        int nb = (int)scomp[1]; if (nb > BAND_CAP) nb = BAND_CAP;
        nband[r] = nb;
        muarr[r] = mu; sinvarr[r] = sinv;
    }
}

// ---------------- K2b: fp64 refinement of band candidates + exact final select --
__global__ __launch_bounds__(256) void refine_select(
    const float* __restrict__ X, const float* __restrict__ Wenc,
    const float* __restrict__ benc, const float* __restrict__ gamma,
    const float* __restrict__ beta, const int* __restrict__ band_idx,
    const int* __restrict__ cdef, const int* __restrict__ nband,
    const float* __restrict__ muarr, const float* __restrict__ sinvarr,
    int* __restrict__ sel_idx, float* __restrict__ sel_val)
{
    __shared__ float xs[DIM];
    __shared__ float cval[BAND_CAP];
    __shared__ int   cidx[BAND_CAP];
    __shared__ int   scnt;
    const int t = threadIdx.x;
    const long r = blockIdx.x;
    const int w = t >> 6, l = t & 63;

    for (int i = t; i < DIM; i += 256) xs[i] = X[r * DIM + i];
    if (t == 0) scnt = 0;
    const int nb = nband[r];
    const int cd = cdef[r];
    int need = TOPK - cd; if (need > nb) need = nb;
    const double mu = (double)muarr[r], sinv = (double)sinvarr[r];
    __syncthreads();

    for (int c = w; c < nb; c += 4) {
        const int fi = band_idx[r * BAND_CAP + c];
        const float* wr = Wenc + (size_t)fi * DIM;
        double s = 0.0;
        for (int k = l; k < DIM; k += 64) s = fma((double)xs[k], (double)wr[k], s);
#pragma unroll
        for (int o = 32; o > 0; o >>= 1) s += __shfl_down(s, o, 64);
        if (l == 0) {
            const double z = s + (double)benc[fi];
            const double a = (z - mu) * sinv * (double)gamma[fi] + (double)beta[fi];
            float af = (float)a;
            cval[c] = fmaxf(af, 0.f);
            cidx[c] = fi;
        }
    }
    __syncthreads();
    if (t < nb) {
        const float v = cval[t];
        const int id = cidx[t];
        int rank = 0;
        for (int j = 0; j < nb; ++j) {
            const float vj = cval[j];
            rank += (vj > v) || (vj == v && cidx[j] < id);
        }
        if (rank < need) {
            const int s = atomicAdd(&scnt, 1);
            sel_idx[r * TOPK + cd + s] = id;
            sel_val[r * TOPK + cd + s] = v;
        }
    }
}

// ---------------- K3: transpose W_dec [768][32768] -> WdT [32768][768] ----------
__global__ __launch_bounds__(256) void transposeWd(
    const float* __restrict__ Wd, float* __restrict__ WdT)
{
    __shared__ float tile[32][33];
    const int fx = blockIdx.x * 32;
    const int dy = blockIdx.y * 32;
    const int tx = threadIdx.x & 31;
    const int ty = threadIdx.x >> 5;
    for (int i = ty; i < 32; i += 8)
        tile[i][tx] = Wd[(size_t)(dy + i) * FDICT + fx + tx];
    __syncthreads();
    for (int i = ty; i < 32; i += 8)
        WdT[(size_t)(fx + i) * DIM + dy + tx] = tile[tx][i];
}

// ---------------- K4: sparse decode ---------------------------------------------
__global__ __launch_bounds__(256) void decode(
    const int* __restrict__ sel_idx, const float* __restrict__ sel_val,
    const float* __restrict__ WdT, const float* __restrict__ bdec,
    float* __restrict__ out)
{
    __shared__ int   sidx[TOPK];
    __shared__ float sval[TOPK];
    const int t = threadIdx.x;
    const long r = blockIdx.x;
    if (t < TOPK) { sidx[t] = sel_idx[r * TOPK + t]; sval[t] = sel_val[r * TOPK + t]; }
    __syncthreads();
    float a0 = bdec[t], a1 = bdec[256 + t], a2 = bdec[512 + t];
    for (int j = 0; j < TOPK; ++j) {
        const float* w = WdT + (size_t)sidx[j] * DIM;
        const float v = sval[j];
        a0 = fmaf(v, w[t], a0);
        a1 = fmaf(v, w[256 + t], a1);
        a2 = fmaf(v, w[512 + t], a2);
    }
    out[r * DIM + t]       = a0;
    out[r * DIM + 256 + t] = a1;
    out[r * DIM + 512 + t] = a2;
}

// ---------------- K5: finalize features: zero row + scatter ----------------------
__global__ __launch_bounds__(1024) void featfill(
    const int* __restrict__ sel_idx, const float* __restrict__ sel_val,
    float* __restrict__ feat)
{
    const int t = threadIdx.x;
    const long r = blockIdx.x;
    float4 z4; z4.x = 0.f; z4.y = 0.f; z4.z = 0.f; z4.w = 0.f;
    float4* row4 = (float4*)(feat + r * FDICT);
    for (int i = t; i < FDICT / 4; i += 1024) row4[i] = z4;
    __syncthreads();
    if (t < TOPK)
        feat[r * FDICT + sel_idx[r * TOPK + t]] = sel_val[r * TOPK + t];
}

extern "C" void kernel_launch(void* const* d_in, const int* in_sizes, int n_in,
                              void* d_out, int out_size, void* d_ws, size_t ws_size,
                              hipStream_t stream)
{
    const float* x     = (const float*)d_in[0];
    const float* Wenc  = (const float*)d_in[1];
    const float* benc  = (const float*)d_in[2];
    const float* gamma = (const float*)d_in[3];
    const float* beta  = (const float*)d_in[4];
    const float* Wdec  = (const float*)d_in[5];
    const float* bdec  = (const float*)d_in[6];

    float* out  = (float*)d_out;
    float* feat = out + (size_t)R_TOT * DIM;          // z scratch then features

    char* ws = (char*)d_ws;
    int*   sidx  = (int*)ws;                                       // 4 MB
    float* sval  = (float*)(ws + (size_t)R_TOT * TOPK * 4);        // 4 MB
    int*   bidx  = (int*)(ws + (size_t)R_TOT * TOPK * 8);          // 3 MB
    int*   cdef  = (int*)(ws + (size_t)R_TOT * (TOPK * 8 + BAND_CAP * 4));
    int*   nbnd  = cdef + R_TOT;
    float* muarr = (float*)(nbnd + R_TOT);
    float* sinva = muarr + R_TOT;

    enc_gemm<<<dim3(R_TOT / 128, FDICT / 128), 256, 0, stream>>>(x, Wenc, benc, feat);
    topk_select<<<R_TOT, 1024, 0, stream>>>(feat, gamma, beta, sidx, sval,
                                            bidx, cdef, nbnd, muarr, sinva);
    refine_select<<<R_TOT, 256, 0, stream>>>(x, Wenc, benc, gamma, beta,
                                             bidx, cdef, nbnd, muarr, sinva,
                                             sidx, sval);
    transposeWd<<<dim3(FDICT / 32, DIM / 32), 256, 0, stream>>>(Wdec, feat);
    decode<<<R_TOT, 256, 0, stream>>>(sidx, sval, feat, bdec, out);
    featfill<<<R_TOT, 1024, 0, stream>>>(sidx, sval, feat);
}

// Round 4
// 2786.674 us; speedup vs baseline: 4.2703x; 1.1575x over previous
//
#include <hip/hip_runtime.h>
#include <hip/hip_bf16.h>

#define R_TOT  8192      // B*S
#define DIM    768       // D
#define FDICT  32768
#define TOPK   128
#define LN_EPS 1e-5f
#define BAND_M 0.12f
#define BAND_CAP 192

using f32x4  = __attribute__((ext_vector_type(4))) float;
using short8 = __attribute__((ext_vector_type(8))) short;

__device__ inline short f2bf(float f) {
    __hip_bfloat16 h = __float2bfloat16(f);
    return *reinterpret_cast<short*>(&h);
}
__device__ inline float bf2f(short s) {
    return __uint_as_float(((unsigned)(unsigned short)s) << 16);
}
__device__ inline void load_lds16(const void* g, void* l) {
    __builtin_amdgcn_global_load_lds(
        (const __attribute__((address_space(1))) unsigned int*)g,
        (__attribute__((address_space(3))) unsigned int*)l, 16, 0, 0);
}

// ---------------- K0: fp32 -> bf16 conversion (grid-stride, 16B stores) ---------
__global__ __launch_bounds__(256) void conv_bf16(
    const float* __restrict__ in, unsigned short* __restrict__ out, int n8)
{
    const int i0 = blockIdx.x * 256 + threadIdx.x;
    const int stride = gridDim.x * 256;
    for (int g = i0; g < n8; g += stride) {
        const float4 a = ((const float4*)in)[g * 2];
        const float4 b = ((const float4*)in)[g * 2 + 1];
        short8 v;
        v[0] = f2bf(a.x); v[1] = f2bf(a.y); v[2] = f2bf(a.z); v[3] = f2bf(a.w);
        v[4] = f2bf(b.x); v[5] = f2bf(b.y); v[6] = f2bf(b.z); v[7] = f2bf(b.w);
        ((short8*)out)[g] = v;
    }
}

// ---------------- K1: encoder GEMM, m97-style (bf16 in, bf16 out) ---------------
// Zb[m,n] = bf16( sum_k Xb[m,k]*Wb[n,k] + b[n] ).  128x128 tile, BK=64, 4 waves.
// global_load_lds width-16 staging into linear LDS [128][64]; ds_read_b128 frags.
__global__ __launch_bounds__(256) void enc_gemm(
    const unsigned short* __restrict__ Xb, const unsigned short* __restrict__ Wb,
    const float* __restrict__ benc, unsigned short* __restrict__ Zb)
{
    __shared__ __align__(16) unsigned short S[16384];  // As | Bs, later Cs overlay
    unsigned short* As = S;
    unsigned short* Bs = S + 8192;

    const int t = threadIdx.x;
    const int w = t >> 6, l = t & 63;

    // XCD-aware swizzle (nwg = 16384, %8 == 0)
    const int cpx = gridDim.x >> 3;
    const int swz = (blockIdx.x & 7) * cpx + (blockIdx.x >> 3);
    const long bm = (long)(swz >> 8) * 128;   // 64 row-blocks
    const long bn = (long)(swz & 255) * 128;  // 256 col-blocks

    const int wm = w >> 1, wn = w & 1;

    // staging: wave w covers rows [w*32, w*32+32); op i covers 8 rows
    const unsigned short* ga = Xb + (bm + w * 32 + (l >> 3)) * DIM + (l & 7) * 8;
    const unsigned short* gb = Wb + (bn + w * 32 + (l >> 3)) * DIM + (l & 7) * 8;
    unsigned short* la = As + (w * 32) * 64;
    unsigned short* lb = Bs + (w * 32) * 64;

    f32x4 acc[4][4];
#pragma unroll
    for (int m = 0; m < 4; ++m)
#pragma unroll
        for (int n = 0; n < 4; ++n) acc[m][n] = (f32x4){0.f, 0.f, 0.f, 0.f};

    const int lrow = l & 15, lk = (l >> 4) * 8;

    for (int kt = 0; kt < DIM / 64; ++kt) {
#pragma unroll
        for (int i = 0; i < 4; ++i) {
            load_lds16(ga + (size_t)i * 8 * DIM, la + i * 512);
            load_lds16(gb + (size_t)i * 8 * DIM, lb + i * 512);
        }
        ga += 64; gb += 64;
        __syncthreads();
#pragma unroll
        for (int ks = 0; ks < 2; ++ks) {
            short8 af[4], bfr[4];
#pragma unroll
            for (int m = 0; m < 4; ++m)
                af[m] = *(const short8*)&As[(wm * 64 + m * 16 + lrow) * 64 + ks * 32 + lk];
#pragma unroll
            for (int n = 0; n < 4; ++n)
                bfr[n] = *(const short8*)&Bs[(wn * 64 + n * 16 + lrow) * 64 + ks * 32 + lk];
#pragma unroll
            for (int m = 0; m < 4; ++m)
#pragma unroll
                for (int n = 0; n < 4; ++n)
                    acc[m][n] = __builtin_amdgcn_mfma_f32_16x16x32_bf16(
                        af[m], bfr[n], acc[m][n], 0, 0, 0);
        }
        __syncthreads();
    }

    // epilogue: bias + cvt to bf16 via LDS Cs[128][128], then coalesced store
    const int lr = l >> 4, lc = l & 15;
    float bias[4];
#pragma unroll
    for (int n = 0; n < 4; ++n) bias[n] = benc[bn + wn * 64 + n * 16 + lc];

    unsigned short* Cs = S;   // overlay (all As/Bs reads done: loop ended with barrier)
#pragma unroll
    for (int m = 0; m < 4; ++m)
#pragma unroll
        for (int n = 0; n < 4; ++n)
#pragma unroll
            for (int q = 0; q < 4; ++q)
                Cs[(wm * 64 + m * 16 + lr * 4 + q) * 128 + wn * 64 + n * 16 + lc] =
                    (unsigned short)f2bf(acc[m][n][q] + bias[n]);
    __syncthreads();
#pragma unroll
    for (int i = 0; i < 8; ++i) {
        const int gidx = t + i * 256;        // 0..2047 granules of 8 shorts
        const int row = gidx >> 4;
        const int c8  = (gidx & 15) * 8;
        *(short8*)&Zb[(bm + row) * FDICT + bn + c8] = *(const short8*)&Cs[row * 128 + c8];
    }
}

// ---------------- K2: stats + LN + approx top-128 + band classification ---------
__global__ __launch_bounds__(1024) void topk_select(
    const unsigned short* __restrict__ Zb, const float* __restrict__ gamma,
    const float* __restrict__ beta, int* __restrict__ sel_idx,
    float* __restrict__ sel_val, int* __restrict__ band_idx,
    int* __restrict__ cdef, int* __restrict__ nband,
    float* __restrict__ muarr, float* __restrict__ sinvarr)
{
    __shared__ unsigned hist[16 * 257];
    __shared__ unsigned finalh[256];
    __shared__ unsigned superh[16];
    __shared__ float    redf[32];
    __shared__ float    sf[2];
    __shared__ unsigned sb[2];
    __shared__ unsigned scomp[2];

    const int t = threadIdx.x;
    const int w = t >> 6;
    const long r = blockIdx.x;

    unsigned u[32];
    float sum = 0.f, sumsq = 0.f;
    const short8* Z8 = (const short8*)(Zb + r * (size_t)FDICT);
#pragma unroll
    for (int q = 0; q < 4; ++q) {
        const short8 v = Z8[q * 1024 + t];
#pragma unroll
        for (int j = 0; j < 8; ++j) {
            const float f = bf2f(v[j]);
            u[q * 8 + j] = __float_as_uint(f);
            sum += f; sumsq += f * f;
        }
    }
#pragma unroll
    for (int o = 32; o > 0; o >>= 1) {
        sum   += __shfl_down(sum, o, 64);
        sumsq += __shfl_down(sumsq, o, 64);
    }
    if ((t & 63) == 0) { redf[w] = sum; redf[16 + w] = sumsq; }
    __syncthreads();
    if (t == 0) {
        float s = 0.f, sq = 0.f;
        for (int i = 0; i < 16; ++i) { s += redf[i]; sq += redf[16 + i]; }
        const float mu = s / (float)FDICT;
        float var = sq / (float)FDICT - mu * mu;
        if (var < 0.f) var = 0.f;
        sf[0] = mu; sf[1] = 1.f / sqrtf(var + LN_EPS);
        scomp[0] = 0; scomp[1] = 0;
    }
    __syncthreads();
    const float mu = sf[0], sinv = sf[1];

#pragma unroll
    for (int q = 0; q < 4; ++q) {
        const size_t base = (size_t)(q * 1024 + t) * 8;
        const float4 g0 = *(const float4*)(gamma + base);
        const float4 g1 = *(const float4*)(gamma + base + 4);
        const float4 b0 = *(const float4*)(beta + base);
        const float4 b1 = *(const float4*)(beta + base + 4);
        const float gs[8] = {g0.x, g0.y, g0.z, g0.w, g1.x, g1.y, g1.z, g1.w};
        const float bs[8] = {b0.x, b0.y, b0.z, b0.w, b1.x, b1.y, b1.z, b1.w};
#pragma unroll
        for (int j = 0; j < 8; ++j) {
            const int i = q * 8 + j;
            u[i] = __float_as_uint(fmaxf(
                fmaf((__uint_as_float(u[i]) - mu) * sinv, gs[j], bs[j]), 0.f));
        }
    }

    // 4-pass byte radix: T = exact bits of 128th largest approx value
    unsigned pfx = 0, cab = 0;
    unsigned* h = &hist[w * 257];
#pragma unroll 1
    for (int p = 0; p < 4; ++p) {
        const int sh = 24 - 8 * p;
        for (int i = t; i < 16 * 257; i += 1024) hist[i] = 0;
        __syncthreads();
        if (p == 0) {
            unsigned zc = 0;
#pragma unroll
            for (int i = 0; i < 32; ++i) {
                const unsigned uu = u[i];
                if (uu == 0u) ++zc; else atomicAdd(&h[uu >> 24], 1u);
            }
            if (zc) atomicAdd(&h[0], zc);
        } else {
#pragma unroll
            for (int i = 0; i < 32; ++i) {
                const unsigned uu = u[i];
                if ((uu >> (sh + 8)) == pfx) atomicAdd(&h[(uu >> sh) & 255u], 1u);
            }
        }
        __syncthreads();
        if (t < 256) {
            unsigned s = 0;
#pragma unroll
            for (int c = 0; c < 16; ++c) s += hist[c * 257 + t];
            finalh[t] = s;
        }
        __syncthreads();
        if (t < 16) {
            unsigned s = 0;
            for (int b = 0; b < 16; ++b) s += finalh[t * 16 + b];
            superh[t] = s;
        }
        __syncthreads();
        if (t == 0) {
            const unsigned need = TOPK - cab;
            unsigned c = 0; int ss = 15;
            for (;;) { const unsigned hs = superh[ss]; if (c + hs >= need) break; c += hs; --ss; }
            int b = ss * 16 + 15;
            for (;;) { const unsigned hb = finalh[b]; if (c + hb >= need) break; c += hb; --b; }
            sb[0] = (unsigned)b; sb[1] = cab + c;
        }
        __syncthreads();
        pfx = (pfx << 8) | sb[0];
        cab = sb[1];
    }

    const float Tf = __uint_as_float(pfx);
    const float thi = Tf + BAND_M, tlo = Tf - BAND_M;

#pragma unroll
    for (int i = 0; i < 32; ++i) {
        const float a = __uint_as_float(u[i]);
        const int idx = ((i >> 3) * 1024 + t) * 8 + (i & 7);
        if (a > thi) {
            const unsigned s = atomicAdd(&scomp[0], 1u);
            sel_idx[r * TOPK + s] = idx;
            sel_val[r * TOPK + s] = a;
        } else if (a >= tlo) {
            const unsigned s = atomicAdd(&scomp[1], 1u);
            if (s < BAND_CAP) band_idx[r * BAND_CAP + s] = idx;
        }
    }
    __syncthreads();
    if (t == 0) {
        cdef[r]  = (int)scomp[0];
        int nb = (int)scomp[1]; if (nb > BAND_CAP) nb = BAND_CAP;
        nband[r] = nb;
        muarr[r] = mu; sinvarr[r] = sinv;
    }
}

// ---------------- K2b: fp64 refinement of band candidates + exact final select --
__global__ __launch_bounds__(256) void refine_select(
    const float* __restrict__ X, const float* __restrict__ Wenc,
    const float* __restrict__ benc, const float* __restrict__ gamma,
    const float* __restrict__ beta, const int* __restrict__ band_idx,
    const int* __restrict__ cdef, const int* __restrict__ nband,
    const float* __restrict__ muarr, const float* __restrict__ sinvarr,
    int* __restrict__ sel_idx, float* __restrict__ sel_val)
{
    __shared__ float xs[DIM];
    __shared__ float cval[BAND_CAP];
    __shared__ int   cidx[BAND_CAP];
    __shared__ int   scnt;
    const int t = threadIdx.x;
    const long r = blockIdx.x;
    const int w = t >> 6, l = t & 63;

    for (int i = t; i < DIM; i += 256) xs[i] = X[r * DIM + i];
    if (t == 0) scnt = 0;
    const int nb = nband[r];
    const int cd = cdef[r];
    int need = TOPK - cd; if (need > nb) need = nb;
    const double mu = (double)muarr[r], sinv = (double)sinvarr[r];
    __syncthreads();

    for (int c = w; c < nb; c += 4) {
        const int fi = band_idx[r * BAND_CAP + c];
        const float* wr = Wenc + (size_t)fi * DIM;
        double s = 0.0;
        for (int k = l; k < DIM; k += 64) s = fma((double)xs[k], (double)wr[k], s);
#pragma unroll
        for (int o = 32; o > 0; o >>= 1) s += __shfl_down(s, o, 64);
        if (l == 0) {
            const double z = s + (double)benc[fi];
            const double a = (z - mu) * sinv * (double)gamma[fi] + (double)beta[fi];
            cval[c] = fmaxf((float)a, 0.f);
            cidx[c] = fi;
        }
    }
    __syncthreads();
    if (t < nb) {
        const float v = cval[t];
        const int id = cidx[t];
        int rank = 0;
        for (int j = 0; j < nb; ++j) {
            const float vj = cval[j];
            rank += (vj > v) || (vj == v && cidx[j] < id);
        }
        if (rank < need) {
            const int s = atomicAdd(&scnt, 1);
            sel_idx[r * TOPK + cd + s] = id;
            sel_val[r * TOPK + cd + s] = v;
        }
    }
}

// ---------------- K3: transpose W_dec [768][32768] -> WdT [32768][768] ----------
__global__ __launch_bounds__(256) void transposeWd(
    const float* __restrict__ Wd, float* __restrict__ WdT)
{
    __shared__ float tile[32][33];
    const int fx = blockIdx.x * 32;
    const int dy = blockIdx.y * 32;
    const int tx = threadIdx.x & 31;
    const int ty = threadIdx.x >> 5;
    for (int i = ty; i < 32; i += 8)
        tile[i][tx] = Wd[(size_t)(dy + i) * FDICT + fx + tx];
    __syncthreads();
    for (int i = ty; i < 32; i += 8)
        WdT[(size_t)(fx + i) * DIM + dy + tx] = tile[tx][i];
}

// ---------------- K4: sparse decode ---------------------------------------------
__global__ __launch_bounds__(256) void decode(
    const int* __restrict__ sel_idx, const float* __restrict__ sel_val,
    const float* __restrict__ WdT, const float* __restrict__ bdec,
    float* __restrict__ out)
{
    __shared__ int   sidx[TOPK];
    __shared__ float sval[TOPK];
    const int t = threadIdx.x;
    const long r = blockIdx.x;
    if (t < TOPK) { sidx[t] = sel_idx[r * TOPK + t]; sval[t] = sel_val[r * TOPK + t]; }
    __syncthreads();
    float a0 = bdec[t], a1 = bdec[256 + t], a2 = bdec[512 + t];
    for (int j = 0; j < TOPK; ++j) {
        const float* wv = WdT + (size_t)sidx[j] * DIM;
        const float v = sval[j];
        a0 = fmaf(v, wv[t], a0);
        a1 = fmaf(v, wv[256 + t], a1);
        a2 = fmaf(v, wv[512 + t], a2);
    }
    out[r * DIM + t]       = a0;
    out[r * DIM + 256 + t] = a1;
    out[r * DIM + 512 + t] = a2;
}

// ---------------- K5: finalize features: zero row + scatter ----------------------
__global__ __launch_bounds__(1024) void featfill(
    const int* __restrict__ sel_idx, const float* __restrict__ sel_val,
    float* __restrict__ feat)
{
    const int t = threadIdx.x;
    const long r = blockIdx.x;
    float4 z4; z4.x = 0.f; z4.y = 0.f; z4.z = 0.f; z4.w = 0.f;
    float4* row4 = (float4*)(feat + r * FDICT);
    for (int i = t; i < FDICT / 4; i += 1024) row4[i] = z4;
    __syncthreads();
    if (t < TOPK)
        feat[r * FDICT + sel_idx[r * TOPK + t]] = sel_val[r * TOPK + t];
}

extern "C" void kernel_launch(void* const* d_in, const int* in_sizes, int n_in,
                              void* d_out, int out_size, void* d_ws, size_t ws_size,
                              hipStream_t stream)
{
    const float* x     = (const float*)d_in[0];
    const float* Wenc  = (const float*)d_in[1];
    const float* benc  = (const float*)d_in[2];
    const float* gamma = (const float*)d_in[3];
    const float* beta  = (const float*)d_in[4];
    const float* Wdec  = (const float*)d_in[5];
    const float* bdec  = (const float*)d_in[6];

    float* out  = (float*)d_out;                      // [8192*768] fp32
    float* feat = out + (size_t)R_TOT * DIM;          // [8192*32768] fp32 region

    // region carving inside the (dead until later) outputs:
    unsigned short* Xb  = (unsigned short*)out;                              // 12.6 MB (dead until decode)
    unsigned short* Zb  = (unsigned short*)feat;                             // 537 MB
    unsigned short* Wb  = (unsigned short*)((char*)feat + 536870912ull);     // 50.3 MB
    float*          WdT = (float*)((char*)feat + 587202560ull);              // 100.7 MB

    char* ws = (char*)d_ws;
    int*   sidx  = (int*)ws;                                        // 4 MB
    float* sval  = (float*)(ws + (size_t)R_TOT * TOPK * 4);         // 4 MB
    int*   bidx  = (int*)(ws + (size_t)R_TOT * TOPK * 8);           // 6.3 MB
    int*   cdef  = (int*)(ws + (size_t)R_TOT * (TOPK * 8 + BAND_CAP * 4));
    int*   nbnd  = cdef + R_TOT;
    float* muarr = (float*)(nbnd + R_TOT);
    float* sinva = muarr + R_TOT;

    conv_bf16<<<1536, 256, 0, stream>>>(x,    Xb, R_TOT * DIM / 8);
    conv_bf16<<<2048, 256, 0, stream>>>(Wenc, Wb, FDICT * DIM / 8);
    enc_gemm<<<16384, 256, 0, stream>>>(Xb, Wb, benc, Zb);
    topk_select<<<R_TOT, 1024, 0, stream>>>(Zb, gamma, beta, sidx, sval,
                                            bidx, cdef, nbnd, muarr, sinva);
    refine_select<<<R_TOT, 256, 0, stream>>>(x, Wenc, benc, gamma, beta,
                                             bidx, cdef, nbnd, muarr, sinva,
                                             sidx, sval);
    transposeWd<<<dim3(FDICT / 32, DIM / 32), 256, 0, stream>>>(Wdec, WdT);
    decode<<<R_TOT, 256, 0, stream>>>(sidx, sval, WdT, bdec, out);
    featfill<<<R_TOT, 1024, 0, stream>>>(sidx, sval, feat);
}

// Round 5
// 2485.992 us; speedup vs baseline: 4.7868x; 1.1210x over previous
//
#include <hip/hip_runtime.h>
#include <hip/hip_bf16.h>

#define R_TOT  8192      // B*S
#define DIM    768       // D
#define FDICT  32768
#define TOPK   128
#define LN_EPS 1e-5f
#define BAND_M 0.12f
#define BAND_CAP 192

using f32x4  = __attribute__((ext_vector_type(4))) float;
using short8 = __attribute__((ext_vector_type(8))) short;

__device__ inline short f2bf(float f) {
    __hip_bfloat16 h = __float2bfloat16(f);
    return *reinterpret_cast<short*>(&h);
}
__device__ inline float bf2f(short s) {
    return __uint_as_float(((unsigned)(unsigned short)s) << 16);
}
__device__ inline void load_lds16(const void* g, void* l) {
    __builtin_amdgcn_global_load_lds(
        (const __attribute__((address_space(1))) unsigned int*)g,
        (__attribute__((address_space(3))) unsigned int*)l, 16, 0, 0);
}

// ---------------- K0: fp32 -> bf16 conversion (grid-stride, 16B stores) ---------
__global__ __launch_bounds__(256) void conv_bf16(
    const float* __restrict__ in, unsigned short* __restrict__ out, int n8)
{
    const int i0 = blockIdx.x * 256 + threadIdx.x;
    const int stride = gridDim.x * 256;
    for (int g = i0; g < n8; g += stride) {
        const float4 a = ((const float4*)in)[g * 2];
        const float4 b = ((const float4*)in)[g * 2 + 1];
        short8 v;
        v[0] = f2bf(a.x); v[1] = f2bf(a.y); v[2] = f2bf(a.z); v[3] = f2bf(a.w);
        v[4] = f2bf(b.x); v[5] = f2bf(b.y); v[6] = f2bf(b.z); v[7] = f2bf(b.w);
        ((short8*)out)[g] = v;
    }
}

// ---------------- K1: encoder GEMM, m97-style (bf16 in, bf16 out) ---------------
__global__ __launch_bounds__(256) void enc_gemm(
    const unsigned short* __restrict__ Xb, const unsigned short* __restrict__ Wb,
    const float* __restrict__ benc, unsigned short* __restrict__ Zb)
{
    __shared__ __align__(16) unsigned short S[16384];  // As | Bs, later Cs overlay
    unsigned short* As = S;
    unsigned short* Bs = S + 8192;

    const int t = threadIdx.x;
    const int w = t >> 6, l = t & 63;

    // XCD-aware swizzle (nwg = 16384, %8 == 0)
    const int cpx = gridDim.x >> 3;
    const int swz = (blockIdx.x & 7) * cpx + (blockIdx.x >> 3);
    const long bm = (long)(swz >> 8) * 128;   // 64 row-blocks
    const long bn = (long)(swz & 255) * 128;  // 256 col-blocks

    const int wm = w >> 1, wn = w & 1;

    const unsigned short* ga = Xb + (bm + w * 32 + (l >> 3)) * DIM + (l & 7) * 8;
    const unsigned short* gb = Wb + (bn + w * 32 + (l >> 3)) * DIM + (l & 7) * 8;
    unsigned short* la = As + (w * 32) * 64;
    unsigned short* lb = Bs + (w * 32) * 64;

    f32x4 acc[4][4];
#pragma unroll
    for (int m = 0; m < 4; ++m)
#pragma unroll
        for (int n = 0; n < 4; ++n) acc[m][n] = (f32x4){0.f, 0.f, 0.f, 0.f};

    const int lrow = l & 15, lk = (l >> 4) * 8;

    for (int kt = 0; kt < DIM / 64; ++kt) {
#pragma unroll
        for (int i = 0; i < 4; ++i) {
            load_lds16(ga + (size_t)i * 8 * DIM, la + i * 512);
            load_lds16(gb + (size_t)i * 8 * DIM, lb + i * 512);
        }
        ga += 64; gb += 64;
        __syncthreads();
#pragma unroll
        for (int ks = 0; ks < 2; ++ks) {
            short8 af[4], bfr[4];
#pragma unroll
            for (int m = 0; m < 4; ++m)
                af[m] = *(const short8*)&As[(wm * 64 + m * 16 + lrow) * 64 + ks * 32 + lk];
#pragma unroll
            for (int n = 0; n < 4; ++n)
                bfr[n] = *(const short8*)&Bs[(wn * 64 + n * 16 + lrow) * 64 + ks * 32 + lk];
#pragma unroll
            for (int m = 0; m < 4; ++m)
#pragma unroll
                for (int n = 0; n < 4; ++n)
                    acc[m][n] = __builtin_amdgcn_mfma_f32_16x16x32_bf16(
                        af[m], bfr[n], acc[m][n], 0, 0, 0);
        }
        __syncthreads();
    }

    // epilogue: bias + cvt to bf16 via LDS Cs[128][128], then coalesced store
    const int lr = l >> 4, lc = l & 15;
    float bias[4];
#pragma unroll
    for (int n = 0; n < 4; ++n) bias[n] = benc[bn + wn * 64 + n * 16 + lc];

    unsigned short* Cs = S;
#pragma unroll
    for (int m = 0; m < 4; ++m)
#pragma unroll
        for (int n = 0; n < 4; ++n)
#pragma unroll
            for (int q = 0; q < 4; ++q)
                Cs[(wm * 64 + m * 16 + lr * 4 + q) * 128 + wn * 64 + n * 16 + lc] =
                    (unsigned short)f2bf(acc[m][n][q] + bias[n]);
    __syncthreads();
#pragma unroll
    for (int i = 0; i < 8; ++i) {
        const int gidx = t + i * 256;
        const int row = gidx >> 4;
        const int c8  = (gidx & 15) * 8;
        *(short8*)&Zb[(bm + row) * FDICT + bn + c8] = *(const short8*)&Cs[row * 128 + c8];
    }
}

// ---------------- K2: stats + LN + bisection threshold + band classification ----
// One block (1024 thr) per row, 32 values/thread in VGPRs. Threshold T found by
// 9-iteration bisection on count(a > thr) — no LDS histograms, no atomic storms.
// Correctness: |T - V128| <= rowmax/2^10 << (BAND_M - approx_err); exact
// selection is restored by refine_select (fp64) over the band.
__global__ __launch_bounds__(1024) void topk_select(
    const unsigned short* __restrict__ Zb, const float* __restrict__ gamma,
    const float* __restrict__ beta, int* __restrict__ sel_idx,
    float* __restrict__ sel_val, int* __restrict__ band_idx,
    int* __restrict__ cdef, int* __restrict__ nband,
    float* __restrict__ muarr, float* __restrict__ sinvarr)
{
    __shared__ float    redf[32];
    __shared__ int      redi[16];
    __shared__ float    sf[3];
    __shared__ int      stot;
    __shared__ unsigned scomp[2];

    const int t = threadIdx.x;
    const int w = t >> 6;
    const long r = blockIdx.x;

    unsigned u[32];
    float sum = 0.f, sumsq = 0.f;
    const short8* Z8 = (const short8*)(Zb + r * (size_t)FDICT);
#pragma unroll
    for (int q = 0; q < 4; ++q) {
        const short8 v = Z8[q * 1024 + t];
#pragma unroll
        for (int j = 0; j < 8; ++j) {
            const float f = bf2f(v[j]);
            u[q * 8 + j] = __float_as_uint(f);
            sum += f; sumsq += f * f;
        }
    }
#pragma unroll
    for (int o = 32; o > 0; o >>= 1) {
        sum   += __shfl_down(sum, o, 64);
        sumsq += __shfl_down(sumsq, o, 64);
    }
    if ((t & 63) == 0) { redf[w] = sum; redf[16 + w] = sumsq; }
    __syncthreads();
    if (t == 0) {
        float s = 0.f, sq = 0.f;
        for (int i = 0; i < 16; ++i) { s += redf[i]; sq += redf[16 + i]; }
        const float mu = s / (float)FDICT;
        float var = sq / (float)FDICT - mu * mu;
        if (var < 0.f) var = 0.f;
        sf[0] = mu; sf[1] = 1.f / sqrtf(var + LN_EPS);
        scomp[0] = 0; scomp[1] = 0;
    }
    __syncthreads();
    const float mu = sf[0], sinv = sf[1];

    // normalize in registers; track per-thread max
    float vmax = 0.f;
#pragma unroll
    for (int q = 0; q < 4; ++q) {
        const size_t base = (size_t)(q * 1024 + t) * 8;
        const float4 g0 = *(const float4*)(gamma + base);
        const float4 g1 = *(const float4*)(gamma + base + 4);
        const float4 b0 = *(const float4*)(beta + base);
        const float4 b1 = *(const float4*)(beta + base + 4);
        const float gs[8] = {g0.x, g0.y, g0.z, g0.w, g1.x, g1.y, g1.z, g1.w};
        const float bs[8] = {b0.x, b0.y, b0.z, b0.w, b1.x, b1.y, b1.z, b1.w};
#pragma unroll
        for (int j = 0; j < 8; ++j) {
            const int i = q * 8 + j;
            const float a = fmaxf(
                fmaf((__uint_as_float(u[i]) - mu) * sinv, gs[j], bs[j]), 0.f);
            u[i] = __float_as_uint(a);
            vmax = fmaxf(vmax, a);
        }
    }
#pragma unroll
    for (int o = 32; o > 0; o >>= 1) vmax = fmaxf(vmax, __shfl_down(vmax, o, 64));
    if ((t & 63) == 0) redf[w] = vmax;
    __syncthreads();
    if (t == 0) {
        float m = 0.f;
        for (int i = 0; i < 16; ++i) m = fmaxf(m, redf[i]);
        sf[2] = m;
    }
    __syncthreads();

    // ---- bisection: V128 in (lo, hi], 9 iterations ----
    float lo = 0.f, hi = sf[2] + 1e-6f;
#pragma unroll 1
    for (int it = 0; it < 9; ++it) {
        const float thr = 0.5f * (lo + hi);
        int cnt = 0;
#pragma unroll
        for (int i = 0; i < 32; ++i) cnt += (__uint_as_float(u[i]) > thr);
#pragma unroll
        for (int o = 32; o > 0; o >>= 1) cnt += __shfl_down(cnt, o, 64);
        if ((t & 63) == 0) redi[w] = cnt;
        __syncthreads();
        if (t == 0) {
            int s = 0;
            for (int i = 0; i < 16; ++i) s += redi[i];
            stot = s;
        }
        __syncthreads();
        if (stot >= TOPK) lo = thr; else hi = thr;
    }
    const float Tf = 0.5f * (lo + hi);
    const float thi = Tf + BAND_M, tlo = Tf - BAND_M;

    // classify: definite-in (> T+M) vs band ([T-M, T+M])
#pragma unroll
    for (int i = 0; i < 32; ++i) {
        const float a = __uint_as_float(u[i]);
        const int idx = ((i >> 3) * 1024 + t) * 8 + (i & 7);
        if (a > thi) {
            const unsigned s = atomicAdd(&scomp[0], 1u);
            sel_idx[r * TOPK + s] = idx;
            sel_val[r * TOPK + s] = a;
        } else if (a >= tlo) {
            const unsigned s = atomicAdd(&scomp[1], 1u);
            if (s < BAND_CAP) band_idx[r * BAND_CAP + s] = idx;
        }
    }
    __syncthreads();
    if (t == 0) {
        cdef[r]  = (int)scomp[0];
        int nb = (int)scomp[1]; if (nb > BAND_CAP) nb = BAND_CAP;
        nband[r] = nb;
        muarr[r] = mu; sinvarr[r] = sinv;
    }
}

// ---------------- K2b: fp64 refinement of band candidates + exact final select --
__global__ __launch_bounds__(256) void refine_select(
    const float* __restrict__ X, const float* __restrict__ Wenc,
    const float* __restrict__ benc, const float* __restrict__ gamma,
    const float* __restrict__ beta, const int* __restrict__ band_idx,
    const int* __restrict__ cdef, const int* __restrict__ nband,
    const float* __restrict__ muarr, const float* __restrict__ sinvarr,
    int* __restrict__ sel_idx, float* __restrict__ sel_val)
{
    __shared__ float xs[DIM];
    __shared__ float cval[BAND_CAP];
    __shared__ int   cidx[BAND_CAP];
    __shared__ int   scnt;
    const int t = threadIdx.x;
    const long r = blockIdx.x;
    const int w = t >> 6, l = t & 63;

    for (int i = t; i < DIM; i += 256) xs[i] = X[r * DIM + i];
    if (t == 0) scnt = 0;
    const int nb = nband[r];
    const int cd = cdef[r];
    int need = TOPK - cd; if (need > nb) need = nb;
    const double mu = (double)muarr[r], sinv = (double)sinvarr[r];
    __syncthreads();

    for (int c = w; c < nb; c += 4) {
        const int fi = band_idx[r * BAND_CAP + c];
        const float* wr = Wenc + (size_t)fi * DIM;
        double s = 0.0;
        for (int k = l; k < DIM; k += 64) s = fma((double)xs[k], (double)wr[k], s);
#pragma unroll
        for (int o = 32; o > 0; o >>= 1) s += __shfl_down(s, o, 64);
        if (l == 0) {
            const double z = s + (double)benc[fi];
            const double a = (z - mu) * sinv * (double)gamma[fi] + (double)beta[fi];
            cval[c] = fmaxf((float)a, 0.f);
            cidx[c] = fi;
        }
    }
    __syncthreads();
    if (t < nb) {
        const float v = cval[t];
        const int id = cidx[t];
        int rank = 0;
        for (int j = 0; j < nb; ++j) {
            const float vj = cval[j];
            rank += (vj > v) || (vj == v && cidx[j] < id);
        }
        if (rank < need) {
            const int s = atomicAdd(&scnt, 1);
            sel_idx[r * TOPK + cd + s] = id;
            sel_val[r * TOPK + cd + s] = v;
        }
    }
}

// ---------------- K3: transpose W_dec [768][32768] -> WdT [32768][768] ----------
__global__ __launch_bounds__(256) void transposeWd(
    const float* __restrict__ Wd, float* __restrict__ WdT)
{
    __shared__ float tile[32][33];
    const int fx = blockIdx.x * 32;
    const int dy = blockIdx.y * 32;
    const int tx = threadIdx.x & 31;
    const int ty = threadIdx.x >> 5;
    for (int i = ty; i < 32; i += 8)
        tile[i][tx] = Wd[(size_t)(dy + i) * FDICT + fx + tx];
    __syncthreads();
    for (int i = ty; i < 32; i += 8)
        WdT[(size_t)(fx + i) * DIM + dy + tx] = tile[tx][i];
}

// ---------------- K4: sparse decode ---------------------------------------------
__global__ __launch_bounds__(256) void decode(
    const int* __restrict__ sel_idx, const float* __restrict__ sel_val,
    const float* __restrict__ WdT, const float* __restrict__ bdec,
    float* __restrict__ out)
{
    __shared__ int   sidx[TOPK];
    __shared__ float sval[TOPK];
    const int t = threadIdx.x;
    const long r = blockIdx.x;
    if (t < TOPK) { sidx[t] = sel_idx[r * TOPK + t]; sval[t] = sel_val[r * TOPK + t]; }
    __syncthreads();
    float a0 = bdec[t], a1 = bdec[256 + t], a2 = bdec[512 + t];
    for (int j = 0; j < TOPK; ++j) {
        const float* wv = WdT + (size_t)sidx[j] * DIM;
        const float v = sval[j];
        a0 = fmaf(v, wv[t], a0);
        a1 = fmaf(v, wv[256 + t], a1);
        a2 = fmaf(v, wv[512 + t], a2);
    }
    out[r * DIM + t]       = a0;
    out[r * DIM + 256 + t] = a1;
    out[r * DIM + 512 + t] = a2;
}

// ---------------- K5: finalize features: zero row + scatter ----------------------
__global__ __launch_bounds__(1024) void featfill(
    const int* __restrict__ sel_idx, const float* __restrict__ sel_val,
    float* __restrict__ feat)
{
    const int t = threadIdx.x;
    const long r = blockIdx.x;
    float4 z4; z4.x = 0.f; z4.y = 0.f; z4.z = 0.f; z4.w = 0.f;
    float4* row4 = (float4*)(feat + r * FDICT);
    for (int i = t; i < FDICT / 4; i += 1024) row4[i] = z4;
    __syncthreads();
    if (t < TOPK)
        feat[r * FDICT + sel_idx[r * TOPK + t]] = sel_val[r * TOPK + t];
}

extern "C" void kernel_launch(void* const* d_in, const int* in_sizes, int n_in,
                              void* d_out, int out_size, void* d_ws, size_t ws_size,
                              hipStream_t stream)
{
    const float* x     = (const float*)d_in[0];
    const float* Wenc  = (const float*)d_in[1];
    const float* benc  = (const float*)d_in[2];
    const float* gamma = (const float*)d_in[3];
    const float* beta  = (const float*)d_in[4];
    const float* Wdec  = (const float*)d_in[5];
    const float* bdec  = (const float*)d_in[6];

    float* out  = (float*)d_out;                      // [8192*768] fp32
    float* feat = out + (size_t)R_TOT * DIM;          // [8192*32768] fp32 region

    unsigned short* Xb  = (unsigned short*)out;                              // 12.6 MB (dead until decode)
    unsigned short* Zb  = (unsigned short*)feat;                             // 537 MB
    unsigned short* Wb  = (unsigned short*)((char*)feat + 536870912ull);     // 50.3 MB
    float*          WdT = (float*)((char*)feat + 587202560ull);              // 100.7 MB

    char* ws = (char*)d_ws;
    int*   sidx  = (int*)ws;                                        // 4 MB
    float* sval  = (float*)(ws + (size_t)R_TOT * TOPK * 4);         // 4 MB
    int*   bidx  = (int*)(ws + (size_t)R_TOT * TOPK * 8);           // 6.3 MB
    int*   cdef  = (int*)(ws + (size_t)R_TOT * (TOPK * 8 + BAND_CAP * 4));
    int*   nbnd  = cdef + R_TOT;
    float* muarr = (float*)(nbnd + R_TOT);
    float* sinva = muarr + R_TOT;

    conv_bf16<<<1536, 256, 0, stream>>>(x,    Xb, R_TOT * DIM / 8);
    conv_bf16<<<2048, 256, 0, stream>>>(Wenc, Wb, FDICT * DIM / 8);
    enc_gemm<<<16384, 256, 0, stream>>>(Xb, Wb, benc, Zb);
    topk_select<<<R_TOT, 1024, 0, stream>>>(Zb, gamma, beta, sidx, sval,
                                            bidx, cdef, nbnd, muarr, sinva);
    refine_select<<<R_TOT, 256, 0, stream>>>(x, Wenc, benc, gamma, beta,
                                             bidx, cdef, nbnd, muarr, sinva,
                                             sidx, sval);
    transposeWd<<<dim3(FDICT / 32, DIM / 32), 256, 0, stream>>>(Wdec, WdT);
    decode<<<R_TOT, 256, 0, stream>>>(sidx, sval, WdT, bdec, out);
    featfill<<<R_TOT, 1024, 0, stream>>>(sidx, sval, feat);
}

// Round 7
// 2189.737 us; speedup vs baseline: 5.4344x; 1.1353x over previous
//
#include <hip/hip_runtime.h>
#include <hip/hip_bf16.h>

#define R_TOT  8192      // B*S
#define DIM    768       // D
#define FDICT  32768
#define TOPK   128
#define LN_EPS 1e-5f
#define BAND_M 0.12f
#define BAND_CAP 192

using f32x4  = __attribute__((ext_vector_type(4))) float;
using short8 = __attribute__((ext_vector_type(8))) short;

__device__ inline short f2bf(float f) {
    __hip_bfloat16 h = __float2bfloat16(f);
    return *reinterpret_cast<short*>(&h);
}
__device__ inline float bf2f(short s) {
    return __uint_as_float(((unsigned)(unsigned short)s) << 16);
}
__device__ inline void load_lds16(const void* g, void* l) {
    __builtin_amdgcn_global_load_lds(
        (const __attribute__((address_space(1))) unsigned int*)g,
        (__attribute__((address_space(3))) unsigned int*)l, 16, 0, 0);
}

// ---------------- K0: fp32 -> bf16 conversion (grid-stride, 16B stores) ---------
__global__ __launch_bounds__(256) void conv_bf16(
    const float* __restrict__ in, unsigned short* __restrict__ out, int n8)
{
    const int i0 = blockIdx.x * 256 + threadIdx.x;
    const int stride = gridDim.x * 256;
    for (int g = i0; g < n8; g += stride) {
        const float4 a = ((const float4*)in)[g * 2];
        const float4 b = ((const float4*)in)[g * 2 + 1];
        short8 v;
        v[0] = f2bf(a.x); v[1] = f2bf(a.y); v[2] = f2bf(a.z); v[3] = f2bf(a.w);
        v[4] = f2bf(b.x); v[5] = f2bf(b.y); v[6] = f2bf(b.z); v[7] = f2bf(b.w);
        ((short8*)out)[g] = v;
    }
}

// ---------------- K1: encoder GEMM, double-buffered LDS + nt-stores -------------
// Zb[m,n] = bf16( sum_k Xb[m,k]*Wb[n,k] + b[n] ).  128x128 tile, BK=64, 4 waves.
// T3-minimum 2-phase: stage tile kt+1 into buf^1 BEFORE computing tile kt;
// one __syncthreads (vmcnt0+barrier) per K-step. Zb written nontemporal so the
// 537MB stream doesn't evict X/W (63MB) from Infinity Cache.
__global__ __launch_bounds__(256) void enc_gemm(
    const unsigned short* __restrict__ Xb, const unsigned short* __restrict__ Wb,
    const float* __restrict__ benc, unsigned short* __restrict__ Zb)
{
    __shared__ __align__(16) unsigned short S[32768];  // As0|Bs0|As1|Bs1 (8192 each)

    const int t = threadIdx.x;
    const int w = t >> 6, l = t & 63;

    // XCD-aware swizzle (nwg = 16384, %8 == 0)
    const int cpx = gridDim.x >> 3;
    const int swz = (blockIdx.x & 7) * cpx + (blockIdx.x >> 3);
    const long bm = (long)(swz >> 8) * 128;   // 64 row-blocks
    const long bn = (long)(swz & 255) * 128;  // 256 col-blocks

    const int wm = w >> 1, wn = w & 1;

    const unsigned short* ga = Xb + (bm + w * 32 + (l >> 3)) * DIM + (l & 7) * 8;
    const unsigned short* gb = Wb + (bn + w * 32 + (l >> 3)) * DIM + (l & 7) * 8;
    const int stg = w * 2048;                 // this wave's staging base (shorts)

    f32x4 acc[4][4];
#pragma unroll
    for (int m = 0; m < 4; ++m)
#pragma unroll
        for (int n = 0; n < 4; ++n) acc[m][n] = (f32x4){0.f, 0.f, 0.f, 0.f};

    const int lrow = l & 15, lk = (l >> 4) * 8;

    // prologue: stage tile 0 into buf0
#pragma unroll
    for (int i = 0; i < 4; ++i) {
        load_lds16(ga + (size_t)i * 8 * DIM, S + stg + i * 512);
        load_lds16(gb + (size_t)i * 8 * DIM, S + 8192 + stg + i * 512);
    }
    ga += 64; gb += 64;
    __syncthreads();

#pragma unroll 1
    for (int kt = 0; kt < DIM / 64 - 1; ++kt) {
        const int nbo = ((kt & 1) ^ 1) * 16384;   // prefetch buffer
        const int cbo = (kt & 1) * 16384;         // compute buffer
        // issue prefetch of tile kt+1 (in flight across this step's compute)
#pragma unroll
        for (int i = 0; i < 4; ++i) {
            load_lds16(ga + (size_t)i * 8 * DIM, S + nbo + stg + i * 512);
            load_lds16(gb + (size_t)i * 8 * DIM, S + nbo + 8192 + stg + i * 512);
        }
        ga += 64; gb += 64;
        // compute tile kt
        const unsigned short* rA = S + cbo;
        const unsigned short* rB = S + cbo + 8192;
#pragma unroll
        for (int ks = 0; ks < 2; ++ks) {
            short8 af[4], bfr[4];
#pragma unroll
            for (int m = 0; m < 4; ++m)
                af[m] = *(const short8*)&rA[(wm * 64 + m * 16 + lrow) * 64 + ks * 32 + lk];
#pragma unroll
            for (int n = 0; n < 4; ++n)
                bfr[n] = *(const short8*)&rB[(wn * 64 + n * 16 + lrow) * 64 + ks * 32 + lk];
#pragma unroll
            for (int m = 0; m < 4; ++m)
#pragma unroll
                for (int n = 0; n < 4; ++n)
                    acc[m][n] = __builtin_amdgcn_mfma_f32_16x16x32_bf16(
                        af[m], bfr[n], acc[m][n], 0, 0, 0);
        }
        __syncthreads();   // drains prefetch (vmcnt0) + lds, flips buffers
    }

    // epilogue compute: last tile (index DIM/64-1 = 11) sits in buf1
    {
        const int cbo = ((DIM / 64 - 1) & 1) * 16384;
        const unsigned short* rA = S + cbo;
        const unsigned short* rB = S + cbo + 8192;
#pragma unroll
        for (int ks = 0; ks < 2; ++ks) {
            short8 af[4], bfr[4];
#pragma unroll
            for (int m = 0; m < 4; ++m)
                af[m] = *(const short8*)&rA[(wm * 64 + m * 16 + lrow) * 64 + ks * 32 + lk];
#pragma unroll
            for (int n = 0; n < 4; ++n)
                bfr[n] = *(const short8*)&rB[(wn * 64 + n * 16 + lrow) * 64 + ks * 32 + lk];
#pragma unroll
            for (int m = 0; m < 4; ++m)
#pragma unroll
                for (int n = 0; n < 4; ++n)
                    acc[m][n] = __builtin_amdgcn_mfma_f32_16x16x32_bf16(
                        af[m], bfr[n], acc[m][n], 0, 0, 0);
        }
    }

    // epilogue: bias + cvt to bf16 via LDS Cs overlay on buf0 (S[0..16383]);
    // last tile was read from buf1, and all buf0 reads ended at the last barrier.
    const int lr = l >> 4, lc = l & 15;
    float bias[4];
#pragma unroll
    for (int n = 0; n < 4; ++n) bias[n] = benc[bn + wn * 64 + n * 16 + lc];

    unsigned short* Cs = S;   // 128x128 bf16 = 32 KB
#pragma unroll
    for (int m = 0; m < 4; ++m)
#pragma unroll
        for (int n = 0; n < 4; ++n)
#pragma unroll
            for (int q = 0; q < 4; ++q)
                Cs[(wm * 64 + m * 16 + lr * 4 + q) * 128 + wn * 64 + n * 16 + lc] =
                    (unsigned short)f2bf(acc[m][n][q] + bias[n]);
    __syncthreads();
#pragma unroll
    for (int i = 0; i < 8; ++i) {
        const int gidx = t + i * 256;
        const int row = gidx >> 4;
        const int c8  = (gidx & 15) * 8;
        const short8 v = *(const short8*)&Cs[row * 128 + c8];
        __builtin_nontemporal_store(v, (short8*)&Zb[(bm + row) * FDICT + bn + c8]);
    }
}

// ---------------- K2: stats + LN + bisection threshold + band classification ----
__global__ __launch_bounds__(1024) void topk_select(
    const unsigned short* __restrict__ Zb, const float* __restrict__ gamma,
    const float* __restrict__ beta, int* __restrict__ sel_idx,
    float* __restrict__ sel_val, int* __restrict__ band_idx,
    int* __restrict__ cdef, int* __restrict__ nband,
    float* __restrict__ muarr, float* __restrict__ sinvarr)
{
    __shared__ float    redf[32];
    __shared__ int      redi[16];
    __shared__ float    sf[3];
    __shared__ int      stot;
    __shared__ unsigned scomp[2];

    const int t = threadIdx.x;
    const int w = t >> 6;
    const long r = blockIdx.x;

    unsigned u[32];
    float sum = 0.f, sumsq = 0.f;
    const short8* Z8 = (const short8*)(Zb + r * (size_t)FDICT);
#pragma unroll
    for (int q = 0; q < 4; ++q) {
        const short8 v = Z8[q * 1024 + t];
#pragma unroll
        for (int j = 0; j < 8; ++j) {
            const float f = bf2f(v[j]);
            u[q * 8 + j] = __float_as_uint(f);
            sum += f; sumsq += f * f;
        }
    }
#pragma unroll
    for (int o = 32; o > 0; o >>= 1) {
        sum   += __shfl_down(sum, o, 64);
        sumsq += __shfl_down(sumsq, o, 64);
    }
    if ((t & 63) == 0) { redf[w] = sum; redf[16 + w] = sumsq; }
    __syncthreads();
    if (t == 0) {
        float s = 0.f, sq = 0.f;
        for (int i = 0; i < 16; ++i) { s += redf[i]; sq += redf[16 + i]; }
        const float mu = s / (float)FDICT;
        float var = sq / (float)FDICT - mu * mu;
        if (var < 0.f) var = 0.f;
        sf[0] = mu; sf[1] = 1.f / sqrtf(var + LN_EPS);
        scomp[0] = 0; scomp[1] = 0;
    }
    __syncthreads();
    const float mu = sf[0], sinv = sf[1];

    float vmax = 0.f;
#pragma unroll
    for (int q = 0; q < 4; ++q) {
        const size_t base = (size_t)(q * 1024 + t) * 8;
        const float4 g0 = *(const float4*)(gamma + base);
        const float4 g1 = *(const float4*)(gamma + base + 4);
        const float4 b0 = *(const float4*)(beta + base);
        const float4 b1 = *(const float4*)(beta + base + 4);
        const float gs[8] = {g0.x, g0.y, g0.z, g0.w, g1.x, g1.y, g1.z, g1.w};
        const float bs[8] = {b0.x, b0.y, b0.z, b0.w, b1.x, b1.y, b1.z, b1.w};
#pragma unroll
        for (int j = 0; j < 8; ++j) {
            const int i = q * 8 + j;
            const float a = fmaxf(
                fmaf((__uint_as_float(u[i]) - mu) * sinv, gs[j], bs[j]), 0.f);
            u[i] = __float_as_uint(a);
            vmax = fmaxf(vmax, a);
        }
    }
#pragma unroll
    for (int o = 32; o > 0; o >>= 1) vmax = fmaxf(vmax, __shfl_down(vmax, o, 64));
    if ((t & 63) == 0) redf[w] = vmax;
    __syncthreads();
    if (t == 0) {
        float m = 0.f;
        for (int i = 0; i < 16; ++i) m = fmaxf(m, redf[i]);
        sf[2] = m;
    }
    __syncthreads();

    // bisection: V128 in (lo, hi], 9 iterations
    float lo = 0.f, hi = sf[2] + 1e-6f;
#pragma unroll 1
    for (int it = 0; it < 9; ++it) {
        const float thr = 0.5f * (lo + hi);
        int cnt = 0;
#pragma unroll
        for (int i = 0; i < 32; ++i) cnt += (__uint_as_float(u[i]) > thr);
#pragma unroll
        for (int o = 32; o > 0; o >>= 1) cnt += __shfl_down(cnt, o, 64);
        if ((t & 63) == 0) redi[w] = cnt;
        __syncthreads();
        if (t == 0) {
            int s = 0;
            for (int i = 0; i < 16; ++i) s += redi[i];
            stot = s;
        }
        __syncthreads();
        if (stot >= TOPK) lo = thr; else hi = thr;
    }
    const float Tf = 0.5f * (lo + hi);
    const float thi = Tf + BAND_M, tlo = Tf - BAND_M;

#pragma unroll
    for (int i = 0; i < 32; ++i) {
        const float a = __uint_as_float(u[i]);
        const int idx = ((i >> 3) * 1024 + t) * 8 + (i & 7);
        if (a > thi) {
            const unsigned s = atomicAdd(&scomp[0], 1u);
            sel_idx[r * TOPK + s] = idx;
            sel_val[r * TOPK + s] = a;
        } else if (a >= tlo) {
            const unsigned s = atomicAdd(&scomp[1], 1u);
            if (s < BAND_CAP) band_idx[r * BAND_CAP + s] = idx;
        }
    }
    __syncthreads();
    if (t == 0) {
        cdef[r]  = (int)scomp[0];
        int nb = (int)scomp[1]; if (nb > BAND_CAP) nb = BAND_CAP;
        nband[r] = nb;
        muarr[r] = mu; sinvarr[r] = sinv;
    }
}

// ---------------- K2b: fp64 refinement of band candidates + exact final select --
__global__ __launch_bounds__(256) void refine_select(
    const float* __restrict__ X, const float* __restrict__ Wenc,
    const float* __restrict__ benc, const float* __restrict__ gamma,
    const float* __restrict__ beta, const int* __restrict__ band_idx,
    const int* __restrict__ cdef, const int* __restrict__ nband,
    const float* __restrict__ muarr, const float* __restrict__ sinvarr,
    int* __restrict__ sel_idx, float* __restrict__ sel_val)
{
    __shared__ float xs[DIM];
    __shared__ float cval[BAND_CAP];
    __shared__ int   cidx[BAND_CAP];
    __shared__ int   scnt;
    const int t = threadIdx.x;
    const long r = blockIdx.x;
    const int w = t >> 6, l = t & 63;

    for (int i = t; i < DIM; i += 256) xs[i] = X[r * DIM + i];
    if (t == 0) scnt = 0;
    const int nb = nband[r];
    const int cd = cdef[r];
    int need = TOPK - cd; if (need > nb) need = nb;
    const double mu = (double)muarr[r], sinv = (double)sinvarr[r];
    __syncthreads();

    for (int c = w; c < nb; c += 4) {
        const int fi = band_idx[r * BAND_CAP + c];
        const float* wr = Wenc + (size_t)fi * DIM;
        double s = 0.0;
        for (int k = l; k < DIM; k += 64) s = fma((double)xs[k], (double)wr[k], s);
#pragma unroll
        for (int o = 32; o > 0; o >>= 1) s += __shfl_down(s, o, 64);
        if (l == 0) {
            const double z = s + (double)benc[fi];
            const double a = (z - mu) * sinv * (double)gamma[fi] + (double)beta[fi];
            cval[c] = fmaxf((float)a, 0.f);
            cidx[c] = fi;
        }
    }
    __syncthreads();
    if (t < nb) {
        const float v = cval[t];
        const int id = cidx[t];
        int rank = 0;
        for (int j = 0; j < nb; ++j) {
            const float vj = cval[j];
            rank += (vj > v) || (vj == v && cidx[j] < id);
        }
        if (rank < need) {
            const int s = atomicAdd(&scnt, 1);
            sel_idx[r * TOPK + cd + s] = id;
            sel_val[r * TOPK + cd + s] = v;
        }
    }
}

// ---------------- K3: transpose W_dec [768][32768] -> WdTb [32768][768] bf16 ----
__global__ __launch_bounds__(256) void transposeWd(
    const float* __restrict__ Wd, unsigned short* __restrict__ WdTb)
{
    __shared__ float tile[32][33];
    const int fx = blockIdx.x * 32;
    const int dy = blockIdx.y * 32;
    const int tx = threadIdx.x & 31;
    const int ty = threadIdx.x >> 5;
    for (int i = ty; i < 32; i += 8)
        tile[i][tx] = Wd[(size_t)(dy + i) * FDICT + fx + tx];
    __syncthreads();
    for (int i = ty; i < 32; i += 8)
        WdTb[(size_t)(fx + i) * DIM + dy + tx] = (unsigned short)f2bf(tile[tx][i]);
}

// ---------------- K4: sparse decode (bf16 W_decT, fp32 math) --------------------
__global__ __launch_bounds__(384) void decode(
    const int* __restrict__ sel_idx, const float* __restrict__ sel_val,
    const unsigned short* __restrict__ WdTb, const float* __restrict__ bdec,
    float* __restrict__ out)
{
    __shared__ int   sidx[TOPK];
    __shared__ float sval[TOPK];
    const int t = threadIdx.x;
    const long r = blockIdx.x;
    if (t < TOPK) { sidx[t] = sel_idx[r * TOPK + t]; sval[t] = sel_val[r * TOPK + t]; }
    __syncthreads();
    const float2 b2 = *(const float2*)(bdec + t * 2);
    float a0 = b2.x, a1 = b2.y;
    for (int j = 0; j < TOPK; ++j) {
        const unsigned wp = *(const unsigned*)(WdTb + (size_t)sidx[j] * DIM + t * 2);
        const float v = sval[j];
        a0 = fmaf(v, __uint_as_float((wp & 0xFFFFu) << 16), a0);
        a1 = fmaf(v, __uint_as_float(wp & 0xFFFF0000u), a1);
    }
    float2 o2; o2.x = a0; o2.y = a1;
    *(float2*)(out + r * DIM + t * 2) = o2;
}

// ---------------- K5: finalize features: zero row (nt) + scatter ----------------
__global__ __launch_bounds__(1024) void featfill(
    const int* __restrict__ sel_idx, const float* __restrict__ sel_val,
    float* __restrict__ feat)
{
    const int t = threadIdx.x;
    const long r = blockIdx.x;
    const f32x4 z4 = (f32x4){0.f, 0.f, 0.f, 0.f};
    f32x4* row4 = (f32x4*)(feat + r * FDICT);
    for (int i = t; i < FDICT / 4; i += 1024)
        __builtin_nontemporal_store(z4, &row4[i]);
    __syncthreads();
    if (t < TOPK)
        feat[r * FDICT + sel_idx[r * TOPK + t]] = sel_val[r * TOPK + t];
}

extern "C" void kernel_launch(void* const* d_in, const int* in_sizes, int n_in,
                              void* d_out, int out_size, void* d_ws, size_t ws_size,
                              hipStream_t stream)
{
    const float* x     = (const float*)d_in[0];
    const float* Wenc  = (const float*)d_in[1];
    const float* benc  = (const float*)d_in[2];
    const float* gamma = (const float*)d_in[3];
    const float* beta  = (const float*)d_in[4];
    const float* Wdec  = (const float*)d_in[5];
    const float* bdec  = (const float*)d_in[6];

    float* out  = (float*)d_out;                      // [8192*768] fp32
    float* feat = out + (size_t)R_TOT * DIM;          // [8192*32768] fp32 region

    unsigned short* Xb   = (unsigned short*)out;                             // 12.6 MB (dead until decode)
    unsigned short* Zb   = (unsigned short*)feat;                            // 537 MB
    unsigned short* Wb   = (unsigned short*)((char*)feat + 536870912ull);    // 50.3 MB
    unsigned short* WdTb = (unsigned short*)((char*)feat + 587202560ull);    // 50.3 MB (bf16)

    char* ws = (char*)d_ws;
    int*   sidx  = (int*)ws;                                        // 4 MB
    float* sval  = (float*)(ws + (size_t)R_TOT * TOPK * 4);         // 4 MB
    int*   bidx  = (int*)(ws + (size_t)R_TOT * TOPK * 8);           // 6.3 MB
    int*   cdef  = (int*)(ws + (size_t)R_TOT * (TOPK * 8 + BAND_CAP * 4));
    int*   nbnd  = cdef + R_TOT;
    float* muarr = (float*)(nbnd + R_TOT);
    float* sinva = muarr + R_TOT;

    conv_bf16<<<1536, 256, 0, stream>>>(x,    Xb, R_TOT * DIM / 8);
    conv_bf16<<<2048, 256, 0, stream>>>(Wenc, Wb, FDICT * DIM / 8);
    enc_gemm<<<16384, 256, 0, stream>>>(Xb, Wb, benc, Zb);
    topk_select<<<R_TOT, 1024, 0, stream>>>(Zb, gamma, beta, sidx, sval,
                                            bidx, cdef, nbnd, muarr, sinva);
    refine_select<<<R_TOT, 256, 0, stream>>>(x, Wenc, benc, gamma, beta,
                                             bidx, cdef, nbnd, muarr, sinva,
                                             sidx, sval);
    transposeWd<<<dim3(FDICT / 32, DIM / 32), 256, 0, stream>>>(Wdec, WdTb);
    decode<<<R_TOT, 384, 0, stream>>>(sidx, sval, WdTb, bdec, out);
    featfill<<<R_TOT, 1024, 0, stream>>>(sidx, sval, feat);
}

// Round 8
// 2040.645 us; speedup vs baseline: 5.8315x; 1.0731x over previous
//
#include <hip/hip_runtime.h>
#include <hip/hip_bf16.h>

#define R_TOT  8192      // B*S
#define DIM    768       // D
#define FDICT  32768
#define TOPK   128
#define LN_EPS 1e-5f
#define BAND_M 0.12f
#define BAND_CAP 192

using f32x4  = __attribute__((ext_vector_type(4))) float;
using short8 = __attribute__((ext_vector_type(8))) short;

__device__ inline short f2bf(float f) {
    __hip_bfloat16 h = __float2bfloat16(f);
    return *reinterpret_cast<short*>(&h);
}
__device__ inline float bf2f(short s) {
    return __uint_as_float(((unsigned)(unsigned short)s) << 16);
}
__device__ inline void load_lds16(const void* g, void* l) {
    __builtin_amdgcn_global_load_lds(
        (const __attribute__((address_space(1))) unsigned int*)g,
        (__attribute__((address_space(3))) unsigned int*)l, 16, 0, 0);
}

// ---------------- K0: fp32 -> bf16 conversion (grid-stride, 16B stores) ---------
__global__ __launch_bounds__(256) void conv_bf16(
    const float* __restrict__ in, unsigned short* __restrict__ out, int n8)
{
    const int i0 = blockIdx.x * 256 + threadIdx.x;
    const int stride = gridDim.x * 256;
    for (int g = i0; g < n8; g += stride) {
        const float4 a = ((const float4*)in)[g * 2];
        const float4 b = ((const float4*)in)[g * 2 + 1];
        short8 v;
        v[0] = f2bf(a.x); v[1] = f2bf(a.y); v[2] = f2bf(a.z); v[3] = f2bf(a.w);
        v[4] = f2bf(b.x); v[5] = f2bf(b.y); v[6] = f2bf(b.z); v[7] = f2bf(b.w);
        ((short8*)out)[g] = v;
    }
}

// ---------------- K1: encoder GEMM — 256x256 tile, 8-wave, 4-phase/K-tile -------
// Zb[m,n] = bf16( sum_k Xb[m,k]*Wb[n,k] + b[n] ).  BK=64, 12 K-tiles.
// T1 XCD swizzle + T2 st-16 XOR swizzle (linear LDS dest, pre-swizzled global
// src, swizzled ds_read) + T3/T4 phase pipeline with counted vmcnt (never 0 in
// steady state) + T5 setprio around MFMA clusters.  LDS 128 KiB (2 bufs).
#define READ_A(P)                                                              \
    af00 = *(const short8*)&Sb[abase + (2*(P))*1024 + sw0];                    \
    af01 = *(const short8*)&Sb[abase + (2*(P))*1024 + sw1];                    \
    af10 = *(const short8*)&Sb[abase + (2*(P)+1)*1024 + sw0];                  \
    af11 = *(const short8*)&Sb[abase + (2*(P)+1)*1024 + sw1];

#define DO_MFMA(P)                                                             \
    __builtin_amdgcn_s_setprio(1);                                             \
    _Pragma("unroll")                                                          \
    for (int n = 0; n < 4; ++n) {                                              \
        acc[2*(P)][n]   = __builtin_amdgcn_mfma_f32_16x16x32_bf16(af00, bf0[n], acc[2*(P)][n],   0,0,0); \
        acc[2*(P)][n]   = __builtin_amdgcn_mfma_f32_16x16x32_bf16(af01, bf1[n], acc[2*(P)][n],   0,0,0); \
        acc[2*(P)+1][n] = __builtin_amdgcn_mfma_f32_16x16x32_bf16(af10, bf0[n], acc[2*(P)+1][n], 0,0,0); \
        acc[2*(P)+1][n] = __builtin_amdgcn_mfma_f32_16x16x32_bf16(af11, bf1[n], acc[2*(P)+1][n], 0,0,0); \
    }                                                                          \
    __builtin_amdgcn_s_setprio(0);

__global__ __launch_bounds__(512, 2) void enc_gemm(
    const unsigned short* __restrict__ Xb, const unsigned short* __restrict__ Wb,
    const float* __restrict__ benc, unsigned short* __restrict__ Zb)
{
    __shared__ __align__(16) unsigned short S[65536];   // 128 KiB: 2 bufs x (A|B)

    const int t = threadIdx.x;
    const int w = t >> 6, l = t & 63;

    // T1: XCD-aware swizzle; nwg = 4096, %8 == 0 (bijective)
    const int cpx = (int)gridDim.x >> 3;
    const int swz = ((int)blockIdx.x & 7) * cpx + ((int)blockIdx.x >> 3);
    const long bm = (long)(swz >> 7) * 256;     // 32 row-blocks
    const long bn = (long)(swz & 127) * 256;    // 128 col-blocks

    const int wm = w >> 2, wn = w & 3;          // 2M x 4N wave grid
    const int lrow = l & 15, l4 = l >> 4;

    // swizzled ds_read slot offsets (shorts) for ks=0,1: slot = (ks*4+l4)^(row&7)
    const int sw0 = ((l4     ) ^ (lrow & 7)) * 8;
    const int sw1 = ((4 + l4 ) ^ (lrow & 7)) * 8;
    const int abase = wm * 8192 + lrow * 64;            // A rows wm*128 + m*16 + lrow
    const int bbase = 16384 + wn * 4096 + lrow * 64;    // B rows wn*64  + n*16 + lrow

    // staging geometry: granule (row rh, dest slot l&7) loads global slot (l&7)^(l>>3)
    const int rh0 = w * 16 + (l >> 3);
    const int rh1 = rh0 + 8;
    const int gsl = ((l & 7) ^ (l >> 3)) * 8;
    const unsigned short* pA00 = Xb + (bm +       rh0) * DIM + gsl;
    const unsigned short* pA01 = Xb + (bm +       rh1) * DIM + gsl;
    const unsigned short* pA10 = Xb + (bm + 128 + rh0) * DIM + gsl;
    const unsigned short* pA11 = Xb + (bm + 128 + rh1) * DIM + gsl;
    const unsigned short* pB00 = Wb + (bn +       rh0) * DIM + gsl;
    const unsigned short* pB01 = Wb + (bn +       rh1) * DIM + gsl;
    const unsigned short* pB10 = Wb + (bn + 128 + rh0) * DIM + gsl;
    const unsigned short* pB11 = Wb + (bn + 128 + rh1) * DIM + gsl;
    const int d00 = w * 1024;          // (w*2+0)*512 shorts
    const int d01 = w * 1024 + 512;    // (w*2+1)*512

    f32x4 acc[8][4];
#pragma unroll
    for (int m = 0; m < 8; ++m)
#pragma unroll
        for (int n = 0; n < 4; ++n) acc[m][n] = (f32x4){0.f, 0.f, 0.f, 0.f};

    // prologue: stage K-tile 0 into buf0 (8 loads/thread outstanding)
    load_lds16(pA00, S + d00);
    load_lds16(pA01, S + d01);
    load_lds16(pA10, S + 8192 + d00);
    load_lds16(pA11, S + 8192 + d01);
    load_lds16(pB00, S + 16384 + d00);
    load_lds16(pB01, S + 16384 + d01);
    load_lds16(pB10, S + 16384 + 8192 + d00);
    load_lds16(pB11, S + 16384 + 8192 + d01);
    pA00 += 64; pA01 += 64; pA10 += 64; pA11 += 64;
    pB00 += 64; pB01 += 64; pB10 += 64; pB11 += 64;

    short8 bf0[4], bf1[4];
    short8 af00, af01, af10, af11;

#pragma unroll 1
    for (int kt = 0; kt < 12; ++kt) {
        const unsigned short* Sb = S + (kt & 1) * 32768;
        unsigned short*       Sn = S + ((kt & 1) ^ 1) * 32768;

        // ---- phase 0: stage A(kt+1); counted wait; B-frags + m0/m1; MFMA ----
        if (kt < 11) {
            load_lds16(pA00, Sn + d00);
            load_lds16(pA01, Sn + d01);
            load_lds16(pA10, Sn + 8192 + d00);
            load_lds16(pA11, Sn + 8192 + d01);
            asm volatile("s_waitcnt vmcnt(4)" ::: "memory");   // kt's 8 done, 4 in flight
        } else {
            asm volatile("s_waitcnt vmcnt(0)" ::: "memory");   // last tile: drain
        }
        __builtin_amdgcn_s_barrier();
#pragma unroll
        for (int n = 0; n < 4; ++n) {
            bf0[n] = *(const short8*)&Sb[bbase + n * 1024 + sw0];
            bf1[n] = *(const short8*)&Sb[bbase + n * 1024 + sw1];
        }
        READ_A(0)
        DO_MFMA(0)
        asm volatile("" ::: "memory");
        __builtin_amdgcn_s_barrier();

        // ---- phase 1: read m2/m3; stage B(kt+1); MFMA ----
        READ_A(1)
        if (kt < 11) {
            load_lds16(pB00, Sn + 16384 + d00);
            load_lds16(pB01, Sn + 16384 + d01);
            load_lds16(pB10, Sn + 16384 + 8192 + d00);
            load_lds16(pB11, Sn + 16384 + 8192 + d01);
        }
        asm volatile("" ::: "memory");
        __builtin_amdgcn_s_barrier();
        DO_MFMA(1)
        asm volatile("" ::: "memory");
        __builtin_amdgcn_s_barrier();

        // ---- phase 2 ----
        READ_A(2)
        asm volatile("" ::: "memory");
        __builtin_amdgcn_s_barrier();
        DO_MFMA(2)
        asm volatile("" ::: "memory");
        __builtin_amdgcn_s_barrier();

        // ---- phase 3 ----
        READ_A(3)
        asm volatile("" ::: "memory");
        __builtin_amdgcn_s_barrier();
        DO_MFMA(3)
        asm volatile("" ::: "memory");
        __builtin_amdgcn_s_barrier();

        pA00 += 64; pA01 += 64; pA10 += 64; pA11 += 64;
        pB00 += 64; pB01 += 64; pB10 += 64; pB11 += 64;
    }

    // ---- epilogue: bias + cvt via Cs[256][256] overlay, coalesced nt-store ----
    __syncthreads();
    float bias[4];
#pragma unroll
    for (int n = 0; n < 4; ++n) bias[n] = benc[bn + wn * 64 + n * 16 + lrow];
    unsigned short* Cs = S;
#pragma unroll
    for (int m = 0; m < 8; ++m)
#pragma unroll
        for (int n = 0; n < 4; ++n)
#pragma unroll
            for (int q = 0; q < 4; ++q)
                Cs[(wm * 128 + m * 16 + l4 * 4 + q) * 256 + wn * 64 + n * 16 + lrow] =
                    (unsigned short)f2bf(acc[m][n][q] + bias[n]);
    __syncthreads();
#pragma unroll
    for (int it = 0; it < 16; ++it) {
        const int g = t + it * 512;
        const int row = g >> 5;
        const int c8 = (g & 31) * 8;
        const short8 v = *(const short8*)&Cs[row * 256 + c8];
        __builtin_nontemporal_store(v, (short8*)&Zb[(bm + row) * FDICT + bn + c8]);
    }
}

// ---------------- K2: stats + LN + bisection threshold + band classification ----
__global__ __launch_bounds__(1024) void topk_select(
    const unsigned short* __restrict__ Zb, const float* __restrict__ gamma,
    const float* __restrict__ beta, int* __restrict__ sel_idx,
    float* __restrict__ sel_val, int* __restrict__ band_idx,
    int* __restrict__ cdef, int* __restrict__ nband,
    float* __restrict__ muarr, float* __restrict__ sinvarr)
{
    __shared__ float    redf[32];
    __shared__ int      redi[16];
    __shared__ float    sf[3];
    __shared__ int      stot;
    __shared__ unsigned scomp[2];

    const int t = threadIdx.x;
    const int w = t >> 6;
    const long r = blockIdx.x;

    unsigned u[32];
    float sum = 0.f, sumsq = 0.f;
    const short8* Z8 = (const short8*)(Zb + r * (size_t)FDICT);
#pragma unroll
    for (int q = 0; q < 4; ++q) {
        const short8 v = Z8[q * 1024 + t];
#pragma unroll
        for (int j = 0; j < 8; ++j) {
            const float f = bf2f(v[j]);
            u[q * 8 + j] = __float_as_uint(f);
            sum += f; sumsq += f * f;
        }
    }
#pragma unroll
    for (int o = 32; o > 0; o >>= 1) {
        sum   += __shfl_down(sum, o, 64);
        sumsq += __shfl_down(sumsq, o, 64);
    }
    if ((t & 63) == 0) { redf[w] = sum; redf[16 + w] = sumsq; }
    __syncthreads();
    if (t == 0) {
        float s = 0.f, sq = 0.f;
        for (int i = 0; i < 16; ++i) { s += redf[i]; sq += redf[16 + i]; }
        const float mu = s / (float)FDICT;
        float var = sq / (float)FDICT - mu * mu;
        if (var < 0.f) var = 0.f;
        sf[0] = mu; sf[1] = 1.f / sqrtf(var + LN_EPS);
        scomp[0] = 0; scomp[1] = 0;
    }
    __syncthreads();
    const float mu = sf[0], sinv = sf[1];

    float vmax = 0.f;
#pragma unroll
    for (int q = 0; q < 4; ++q) {
        const size_t base = (size_t)(q * 1024 + t) * 8;
        const float4 g0 = *(const float4*)(gamma + base);
        const float4 g1 = *(const float4*)(gamma + base + 4);
        const float4 b0 = *(const float4*)(beta + base);
        const float4 b1 = *(const float4*)(beta + base + 4);
        const float gs[8] = {g0.x, g0.y, g0.z, g0.w, g1.x, g1.y, g1.z, g1.w};
        const float bs[8] = {b0.x, b0.y, b0.z, b0.w, b1.x, b1.y, b1.z, b1.w};
#pragma unroll
        for (int j = 0; j < 8; ++j) {
            const int i = q * 8 + j;
            const float a = fmaxf(
                fmaf((__uint_as_float(u[i]) - mu) * sinv, gs[j], bs[j]), 0.f);
            u[i] = __float_as_uint(a);
            vmax = fmaxf(vmax, a);
        }
    }
#pragma unroll
    for (int o = 32; o > 0; o >>= 1) vmax = fmaxf(vmax, __shfl_down(vmax, o, 64));
    if ((t & 63) == 0) redf[w] = vmax;
    __syncthreads();
    if (t == 0) {
        float m = 0.f;
        for (int i = 0; i < 16; ++i) m = fmaxf(m, redf[i]);
        sf[2] = m;
    }
    __syncthreads();

    // bisection: V128 in (lo, hi], 9 iterations
    float lo = 0.f, hi = sf[2] + 1e-6f;
#pragma unroll 1
    for (int it = 0; it < 9; ++it) {
        const float thr = 0.5f * (lo + hi);
        int cnt = 0;
#pragma unroll
        for (int i = 0; i < 32; ++i) cnt += (__uint_as_float(u[i]) > thr);
#pragma unroll
        for (int o = 32; o > 0; o >>= 1) cnt += __shfl_down(cnt, o, 64);
        if ((t & 63) == 0) redi[w] = cnt;
        __syncthreads();
        if (t == 0) {
            int s = 0;
            for (int i = 0; i < 16; ++i) s += redi[i];
            stot = s;
        }
        __syncthreads();
        if (stot >= TOPK) lo = thr; else hi = thr;
    }
    const float Tf = 0.5f * (lo + hi);
    const float thi = Tf + BAND_M, tlo = Tf - BAND_M;

#pragma unroll
    for (int i = 0; i < 32; ++i) {
        const float a = __uint_as_float(u[i]);
        const int idx = ((i >> 3) * 1024 + t) * 8 + (i & 7);
        if (a > thi) {
            const unsigned s = atomicAdd(&scomp[0], 1u);
            sel_idx[r * TOPK + s] = idx;
            sel_val[r * TOPK + s] = a;
        } else if (a >= tlo) {
            const unsigned s = atomicAdd(&scomp[1], 1u);
            if (s < BAND_CAP) band_idx[r * BAND_CAP + s] = idx;
        }
    }
    __syncthreads();
    if (t == 0) {
        cdef[r]  = (int)scomp[0];
        int nb = (int)scomp[1]; if (nb > BAND_CAP) nb = BAND_CAP;
        nband[r] = nb;
        muarr[r] = mu; sinvarr[r] = sinv;
    }
}

// ---------------- K2b: fp64 refinement of band candidates + exact final select --
__global__ __launch_bounds__(256) void refine_select(
    const float* __restrict__ X, const float* __restrict__ Wenc,
    const float* __restrict__ benc, const float* __restrict__ gamma,
    const float* __restrict__ beta, const int* __restrict__ band_idx,
    const int* __restrict__ cdef, const int* __restrict__ nband,
    const float* __restrict__ muarr, const float* __restrict__ sinvarr,
    int* __restrict__ sel_idx, float* __restrict__ sel_val)
{
    __shared__ float xs[DIM];
    __shared__ float cval[BAND_CAP];
    __shared__ int   cidx[BAND_CAP];
    __shared__ int   scnt;
    const int t = threadIdx.x;
    const long r = blockIdx.x;
    const int w = t >> 6, l = t & 63;

    for (int i = t; i < DIM; i += 256) xs[i] = X[r * DIM + i];
    if (t == 0) scnt = 0;
    const int nb = nband[r];
    const int cd = cdef[r];
    int need = TOPK - cd; if (need > nb) need = nb;
    const double mu = (double)muarr[r], sinv = (double)sinvarr[r];
    __syncthreads();

    for (int c = w; c < nb; c += 4) {
        const int fi = band_idx[r * BAND_CAP + c];
        const float* wr = Wenc + (size_t)fi * DIM;
        double s = 0.0;
        for (int k = l; k < DIM; k += 64) s = fma((double)xs[k], (double)wr[k], s);
#pragma unroll
        for (int o = 32; o > 0; o >>= 1) s += __shfl_down(s, o, 64);
        if (l == 0) {
            const double z = s + (double)benc[fi];
            const double a = (z - mu) * sinv * (double)gamma[fi] + (double)beta[fi];
            cval[c] = fmaxf((float)a, 0.f);
            cidx[c] = fi;
        }
    }
    __syncthreads();
    if (t < nb) {
        const float v = cval[t];
        const int id = cidx[t];
        int rank = 0;
        for (int j = 0; j < nb; ++j) {
            const float vj = cval[j];
            rank += (vj > v) || (vj == v && cidx[j] < id);
        }
        if (rank < need) {
            const int s = atomicAdd(&scnt, 1);
            sel_idx[r * TOPK + cd + s] = id;
            sel_val[r * TOPK + cd + s] = v;
        }
    }
}

// ---------------- K3: transpose W_dec [768][32768] -> WdTb [32768][768] bf16 ----
__global__ __launch_bounds__(256) void transposeWd(
    const float* __restrict__ Wd, unsigned short* __restrict__ WdTb)
{
    __shared__ float tile[32][33];
    const int fx = blockIdx.x * 32;
    const int dy = blockIdx.y * 32;
    const int tx = threadIdx.x & 31;
    const int ty = threadIdx.x >> 5;
    for (int i = ty; i < 32; i += 8)
        tile[i][tx] = Wd[(size_t)(dy + i) * FDICT + fx + tx];
    __syncthreads();
    for (int i = ty; i < 32; i += 8)
        WdTb[(size_t)(fx + i) * DIM + dy + tx] = (unsigned short)f2bf(tile[tx][i]);
}

// ---------------- K4: sparse decode (bf16 W_decT, fp32 math) --------------------
__global__ __launch_bounds__(384) void decode(
    const int* __restrict__ sel_idx, const float* __restrict__ sel_val,
    const unsigned short* __restrict__ WdTb, const float* __restrict__ bdec,
    float* __restrict__ out)
{
    __shared__ int   sidx[TOPK];
    __shared__ float sval[TOPK];
    const int t = threadIdx.x;
    const long r = blockIdx.x;
    if (t < TOPK) { sidx[t] = sel_idx[r * TOPK + t]; sval[t] = sel_val[r * TOPK + t]; }
    __syncthreads();
    const float2 b2 = *(const float2*)(bdec + t * 2);
    float a0 = b2.x, a1 = b2.y;
    for (int j = 0; j < TOPK; ++j) {
        const unsigned wp = *(const unsigned*)(WdTb + (size_t)sidx[j] * DIM + t * 2);
        const float v = sval[j];
        a0 = fmaf(v, __uint_as_float((wp & 0xFFFFu) << 16), a0);
        a1 = fmaf(v, __uint_as_float(wp & 0xFFFF0000u), a1);
    }
    float2 o2; o2.x = a0; o2.y = a1;
    *(float2*)(out + r * DIM + t * 2) = o2;
}

// ---------------- K5: finalize features: zero row (nt) + scatter ----------------
__global__ __launch_bounds__(1024) void featfill(
    const int* __restrict__ sel_idx, const float* __restrict__ sel_val,
    float* __restrict__ feat)
{
    const int t = threadIdx.x;
    const long r = blockIdx.x;
    const f32x4 z4 = (f32x4){0.f, 0.f, 0.f, 0.f};
    f32x4* row4 = (f32x4*)(feat + r * FDICT);
    for (int i = t; i < FDICT / 4; i += 1024)
        __builtin_nontemporal_store(z4, &row4[i]);
    __syncthreads();
    if (t < TOPK)
        feat[r * FDICT + sel_idx[r * TOPK + t]] = sel_val[r * TOPK + t];
}

extern "C" void kernel_launch(void* const* d_in, const int* in_sizes, int n_in,
                              void* d_out, int out_size, void* d_ws, size_t ws_size,
                              hipStream_t stream)
{
    const float* x     = (const float*)d_in[0];
    const float* Wenc  = (const float*)d_in[1];
    const float* benc  = (const float*)d_in[2];
    const float* gamma = (const float*)d_in[3];
    const float* beta  = (const float*)d_in[4];
    const float* Wdec  = (const float*)d_in[5];
    const float* bdec  = (const float*)d_in[6];

    float* out  = (float*)d_out;                      // [8192*768] fp32
    float* feat = out + (size_t)R_TOT * DIM;          // [8192*32768] fp32 region

    unsigned short* Xb   = (unsigned short*)out;                             // 12.6 MB (dead until decode)
    unsigned short* Zb   = (unsigned short*)feat;                            // 537 MB
    unsigned short* Wb   = (unsigned short*)((char*)feat + 536870912ull);    // 50.3 MB
    unsigned short* WdTb = (unsigned short*)((char*)feat + 587202560ull);    // 50.3 MB (bf16)

    char* ws = (char*)d_ws;
    int*   sidx  = (int*)ws;                                        // 4 MB
    float* sval  = (float*)(ws + (size_t)R_TOT * TOPK * 4);         // 4 MB
    int*   bidx  = (int*)(ws + (size_t)R_TOT * TOPK * 8);           // 6.3 MB
    int*   cdef  = (int*)(ws + (size_t)R_TOT * (TOPK * 8 + BAND_CAP * 4));
    int*   nbnd  = cdef + R_TOT;
    float* muarr = (float*)(nbnd + R_TOT);
    float* sinva = muarr + R_TOT;

    conv_bf16<<<1536, 256, 0, stream>>>(x,    Xb, R_TOT * DIM / 8);
    conv_bf16<<<2048, 256, 0, stream>>>(Wenc, Wb, FDICT * DIM / 8);
    enc_gemm<<<4096, 512, 0, stream>>>(Xb, Wb, benc, Zb);
    topk_select<<<R_TOT, 1024, 0, stream>>>(Zb, gamma, beta, sidx, sval,
                                            bidx, cdef, nbnd, muarr, sinva);
    refine_select<<<R_TOT, 256, 0, stream>>>(x, Wenc, benc, gamma, beta,
                                             bidx, cdef, nbnd, muarr, sinva,
                                             sidx, sval);
    transposeWd<<<dim3(FDICT / 32, DIM / 32), 256, 0, stream>>>(Wdec, WdTb);
    decode<<<R_TOT, 384, 0, stream>>>(sidx, sval, WdTb, bdec, out);
    featfill<<<R_TOT, 1024, 0, stream>>>(sidx, sval, feat);
}

// Round 9
// 1914.616 us; speedup vs baseline: 6.2153x; 1.0658x over previous
//
#include <hip/hip_runtime.h>
#include <hip/hip_bf16.h>

#define R_TOT  8192      // B*S
#define DIM    768       // D
#define FDICT  32768
#define TOPK   128
#define LN_EPS 1e-5f
#define BAND_M 0.12f
#define BAND_CAP 192

using f32x4  = __attribute__((ext_vector_type(4))) float;
using short8 = __attribute__((ext_vector_type(8))) short;

__device__ inline short f2bf(float f) {
    __hip_bfloat16 h = __float2bfloat16(f);
    return *reinterpret_cast<short*>(&h);
}
__device__ inline float bf2f(short s) {
    return __uint_as_float(((unsigned)(unsigned short)s) << 16);
}
__device__ inline void load_lds16(const void* g, void* l) {
    __builtin_amdgcn_global_load_lds(
        (const __attribute__((address_space(1))) unsigned int*)g,
        (__attribute__((address_space(3))) unsigned int*)l, 16, 0, 0);
}

// ---------------- K0: fp32 -> bf16 conversion (grid-stride, 16B stores) ---------
__global__ __launch_bounds__(256) void conv_bf16(
    const float* __restrict__ in, unsigned short* __restrict__ out, int n8)
{
    const int i0 = blockIdx.x * 256 + threadIdx.x;
    const int stride = gridDim.x * 256;
    for (int g = i0; g < n8; g += stride) {
        const float4 a = ((const float4*)in)[g * 2];
        const float4 b = ((const float4*)in)[g * 2 + 1];
        short8 v;
        v[0] = f2bf(a.x); v[1] = f2bf(a.y); v[2] = f2bf(a.z); v[3] = f2bf(a.w);
        v[4] = f2bf(b.x); v[5] = f2bf(b.y); v[6] = f2bf(b.z); v[7] = f2bf(b.w);
        ((short8*)out)[g] = v;
    }
}

// ---------------- K1: encoder GEMM — 256x256 tile, 8-wave, 4-phase/K-tile -------
#define READ_A(P)                                                              \
    af00 = *(const short8*)&Sb[abase + (2*(P))*1024 + sw0];                    \
    af01 = *(const short8*)&Sb[abase + (2*(P))*1024 + sw1];                    \
    af10 = *(const short8*)&Sb[abase + (2*(P)+1)*1024 + sw0];                  \
    af11 = *(const short8*)&Sb[abase + (2*(P)+1)*1024 + sw1];

#define DO_MFMA(P)                                                             \
    __builtin_amdgcn_s_setprio(1);                                             \
    _Pragma("unroll")                                                          \
    for (int n = 0; n < 4; ++n) {                                              \
        acc[2*(P)][n]   = __builtin_amdgcn_mfma_f32_16x16x32_bf16(af00, bf0[n], acc[2*(P)][n],   0,0,0); \
        acc[2*(P)][n]   = __builtin_amdgcn_mfma_f32_16x16x32_bf16(af01, bf1[n], acc[2*(P)][n],   0,0,0); \
        acc[2*(P)+1][n] = __builtin_amdgcn_mfma_f32_16x16x32_bf16(af10, bf0[n], acc[2*(P)+1][n], 0,0,0); \
        acc[2*(P)+1][n] = __builtin_amdgcn_mfma_f32_16x16x32_bf16(af11, bf1[n], acc[2*(P)+1][n], 0,0,0); \
    }                                                                          \
    __builtin_amdgcn_s_setprio(0);

__global__ __launch_bounds__(512, 2) void enc_gemm(
    const unsigned short* __restrict__ Xb, const unsigned short* __restrict__ Wb,
    const float* __restrict__ benc, unsigned short* __restrict__ Zb)
{
    __shared__ __align__(16) unsigned short S[65536];   // 128 KiB: 2 bufs x (A|B)

    const int t = threadIdx.x;
    const int w = t >> 6, l = t & 63;

    const int cpx = (int)gridDim.x >> 3;
    const int swz = ((int)blockIdx.x & 7) * cpx + ((int)blockIdx.x >> 3);
    const long bm = (long)(swz >> 7) * 256;
    const long bn = (long)(swz & 127) * 256;

    const int wm = w >> 2, wn = w & 3;
    const int lrow = l & 15, l4 = l >> 4;

    const int sw0 = ((l4     ) ^ (lrow & 7)) * 8;
    const int sw1 = ((4 + l4 ) ^ (lrow & 7)) * 8;
    const int abase = wm * 8192 + lrow * 64;
    const int bbase = 16384 + wn * 4096 + lrow * 64;

    const int rh0 = w * 16 + (l >> 3);
    const int rh1 = rh0 + 8;
    const int gsl = ((l & 7) ^ (l >> 3)) * 8;
    const unsigned short* pA00 = Xb + (bm +       rh0) * DIM + gsl;
    const unsigned short* pA01 = Xb + (bm +       rh1) * DIM + gsl;
    const unsigned short* pA10 = Xb + (bm + 128 + rh0) * DIM + gsl;
    const unsigned short* pA11 = Xb + (bm + 128 + rh1) * DIM + gsl;
    const unsigned short* pB00 = Wb + (bn +       rh0) * DIM + gsl;
    const unsigned short* pB01 = Wb + (bn +       rh1) * DIM + gsl;
    const unsigned short* pB10 = Wb + (bn + 128 + rh0) * DIM + gsl;
    const unsigned short* pB11 = Wb + (bn + 128 + rh1) * DIM + gsl;
    const int d00 = w * 1024;
    const int d01 = w * 1024 + 512;

    f32x4 acc[8][4];
#pragma unroll
    for (int m = 0; m < 8; ++m)
#pragma unroll
        for (int n = 0; n < 4; ++n) acc[m][n] = (f32x4){0.f, 0.f, 0.f, 0.f};

    load_lds16(pA00, S + d00);
    load_lds16(pA01, S + d01);
    load_lds16(pA10, S + 8192 + d00);
    load_lds16(pA11, S + 8192 + d01);
    load_lds16(pB00, S + 16384 + d00);
    load_lds16(pB01, S + 16384 + d01);
    load_lds16(pB10, S + 16384 + 8192 + d00);
    load_lds16(pB11, S + 16384 + 8192 + d01);
    pA00 += 64; pA01 += 64; pA10 += 64; pA11 += 64;
    pB00 += 64; pB01 += 64; pB10 += 64; pB11 += 64;

    short8 bf0[4], bf1[4];
    short8 af00, af01, af10, af11;

#pragma unroll 1
    for (int kt = 0; kt < 12; ++kt) {
        const unsigned short* Sb = S + (kt & 1) * 32768;
        unsigned short*       Sn = S + ((kt & 1) ^ 1) * 32768;

        if (kt < 11) {
            load_lds16(pA00, Sn + d00);
            load_lds16(pA01, Sn + d01);
            load_lds16(pA10, Sn + 8192 + d00);
            load_lds16(pA11, Sn + 8192 + d01);
            asm volatile("s_waitcnt vmcnt(4)" ::: "memory");
        } else {
            asm volatile("s_waitcnt vmcnt(0)" ::: "memory");
        }
        __builtin_amdgcn_s_barrier();
#pragma unroll
        for (int n = 0; n < 4; ++n) {
            bf0[n] = *(const short8*)&Sb[bbase + n * 1024 + sw0];
            bf1[n] = *(const short8*)&Sb[bbase + n * 1024 + sw1];
        }
        READ_A(0)
        DO_MFMA(0)
        asm volatile("" ::: "memory");
        __builtin_amdgcn_s_barrier();

        READ_A(1)
        if (kt < 11) {
            load_lds16(pB00, Sn + 16384 + d00);
            load_lds16(pB01, Sn + 16384 + d01);
            load_lds16(pB10, Sn + 16384 + 8192 + d00);
            load_lds16(pB11, Sn + 16384 + 8192 + d01);
        }
        asm volatile("" ::: "memory");
        __builtin_amdgcn_s_barrier();
        DO_MFMA(1)
        asm volatile("" ::: "memory");
        __builtin_amdgcn_s_barrier();

        READ_A(2)
        asm volatile("" ::: "memory");
        __builtin_amdgcn_s_barrier();
        DO_MFMA(2)
        asm volatile("" ::: "memory");
        __builtin_amdgcn_s_barrier();

        READ_A(3)
        asm volatile("" ::: "memory");
        __builtin_amdgcn_s_barrier();
        DO_MFMA(3)
        asm volatile("" ::: "memory");
        __builtin_amdgcn_s_barrier();

        pA00 += 64; pA01 += 64; pA10 += 64; pA11 += 64;
        pB00 += 64; pB01 += 64; pB10 += 64; pB11 += 64;
    }

    __syncthreads();
    float bias[4];
#pragma unroll
    for (int n = 0; n < 4; ++n) bias[n] = benc[bn + wn * 64 + n * 16 + lrow];
    unsigned short* Cs = S;
#pragma unroll
    for (int m = 0; m < 8; ++m)
#pragma unroll
        for (int n = 0; n < 4; ++n)
#pragma unroll
            for (int q = 0; q < 4; ++q)
                Cs[(wm * 128 + m * 16 + l4 * 4 + q) * 256 + wn * 64 + n * 16 + lrow] =
                    (unsigned short)f2bf(acc[m][n][q] + bias[n]);
    __syncthreads();
#pragma unroll
    for (int it = 0; it < 16; ++it) {
        const int g = t + it * 512;
        const int row = g >> 5;
        const int c8 = (g & 31) * 8;
        const short8 v = *(const short8*)&Cs[row * 256 + c8];
        __builtin_nontemporal_store(v, (short8*)&Zb[(bm + row) * FDICT + bn + c8]);
    }
}

// ---------------- K2: stats + LN + bisection + classify (+ fused feat row) ------
// One block (1024 thr) per row, 32 values/thread in VGPRs.  If feat != nullptr,
// this kernel also zero-fills the feature row (nt) and scatters definite-ins;
// refine_select scatters the band winners afterward.
__global__ __launch_bounds__(1024) void topk_select(
    const unsigned short* __restrict__ Zb, const float* __restrict__ gamma,
    const float* __restrict__ beta, int* __restrict__ sel_idx,
    float* __restrict__ sel_val, int* __restrict__ band_idx,
    int* __restrict__ cdef, int* __restrict__ nband,
    float* __restrict__ muarr, float* __restrict__ sinvarr,
    float* __restrict__ feat)
{
    __shared__ float    redf[32];
    __shared__ float    redm[16];
    __shared__ int      redi[2][16];
    __shared__ unsigned scomp[2];

    const int t = threadIdx.x;
    const int w = t >> 6;
    const long r = blockIdx.x;

    unsigned u[32];
    float sum = 0.f, sumsq = 0.f;
    const short8* Z8 = (const short8*)(Zb + r * (size_t)FDICT);
#pragma unroll
    for (int q = 0; q < 4; ++q) {
        const short8 v = Z8[q * 1024 + t];
#pragma unroll
        for (int j = 0; j < 8; ++j) {
            const float f = bf2f(v[j]);
            u[q * 8 + j] = __float_as_uint(f);
            sum += f; sumsq += f * f;
        }
    }
    if (t == 0) { scomp[0] = 0; scomp[1] = 0; }

    // fused: zero this feature row (overlaps with reduction/bisection below)
    if (feat) {
        const f32x4 z4 = (f32x4){0.f, 0.f, 0.f, 0.f};
        f32x4* row4 = (f32x4*)(feat + r * (size_t)FDICT);
#pragma unroll
        for (int q = 0; q < 8; ++q)
            __builtin_nontemporal_store(z4, &row4[q * 1024 + t]);
    }

#pragma unroll
    for (int o = 32; o > 0; o >>= 1) {
        sum   += __shfl_down(sum, o, 64);
        sumsq += __shfl_down(sumsq, o, 64);
    }
    if ((t & 63) == 0) { redf[w] = sum; redf[16 + w] = sumsq; }
    __syncthreads();
    float s_ = 0.f, sq_ = 0.f;
#pragma unroll
    for (int i = 0; i < 16; ++i) { s_ += redf[i]; sq_ += redf[16 + i]; }
    const float mu = s_ / (float)FDICT;
    float var = sq_ / (float)FDICT - mu * mu;
    if (var < 0.f) var = 0.f;
    const float sinv = 1.f / sqrtf(var + LN_EPS);

    float vmax = 0.f;
#pragma unroll
    for (int q = 0; q < 4; ++q) {
        const size_t base = (size_t)(q * 1024 + t) * 8;
        const float4 g0 = *(const float4*)(gamma + base);
        const float4 g1 = *(const float4*)(gamma + base + 4);
        const float4 b0 = *(const float4*)(beta + base);
        const float4 b1 = *(const float4*)(beta + base + 4);
        const float gs[8] = {g0.x, g0.y, g0.z, g0.w, g1.x, g1.y, g1.z, g1.w};
        const float bs[8] = {b0.x, b0.y, b0.z, b0.w, b1.x, b1.y, b1.z, b1.w};
#pragma unroll
        for (int j = 0; j < 8; ++j) {
            const int i = q * 8 + j;
            const float a = fmaxf(
                fmaf((__uint_as_float(u[i]) - mu) * sinv, gs[j], bs[j]), 0.f);
            u[i] = __float_as_uint(a);
            vmax = fmaxf(vmax, a);
        }
    }
#pragma unroll
    for (int o = 32; o > 0; o >>= 1) vmax = fmaxf(vmax, __shfl_down(vmax, o, 64));
    if ((t & 63) == 0) redm[w] = vmax;
    __syncthreads();
    float m_ = 0.f;
#pragma unroll
    for (int i = 0; i < 16; ++i) m_ = fmaxf(m_, redm[i]);

    // bisection: V128 in (lo, hi], 9 iterations, ONE barrier each
    float lo = 0.f, hi = m_ + 1e-6f;
#pragma unroll 1
    for (int it = 0; it < 9; ++it) {
        const float thr = 0.5f * (lo + hi);
        int cnt = 0;
#pragma unroll
        for (int i = 0; i < 32; ++i) cnt += (__uint_as_float(u[i]) > thr);
#pragma unroll
        for (int o = 32; o > 0; o >>= 1) cnt += __shfl_down(cnt, o, 64);
        if ((t & 63) == 0) redi[it & 1][w] = cnt;
        __syncthreads();
        int stot = 0;
#pragma unroll
        for (int i = 0; i < 16; ++i) stot += redi[it & 1][i];
        if (stot >= TOPK) lo = thr; else hi = thr;
    }
    const float Tf = 0.5f * (lo + hi);
    const float thi = Tf + BAND_M, tlo = Tf - BAND_M;

#pragma unroll
    for (int i = 0; i < 32; ++i) {
        const float a = __uint_as_float(u[i]);
        const int idx = ((i >> 3) * 1024 + t) * 8 + (i & 7);
        if (a > thi) {
            const unsigned s = atomicAdd(&scomp[0], 1u);
            sel_idx[r * TOPK + s] = idx;
            sel_val[r * TOPK + s] = a;
            if (feat) feat[r * (size_t)FDICT + idx] = a;
        } else if (a >= tlo) {
            const unsigned s = atomicAdd(&scomp[1], 1u);
            if (s < BAND_CAP) band_idx[r * BAND_CAP + s] = idx;
        }
    }
    __syncthreads();
    if (t == 0) {
        cdef[r]  = (int)scomp[0];
        int nb = (int)scomp[1]; if (nb > BAND_CAP) nb = BAND_CAP;
        nband[r] = nb;
        muarr[r] = mu; sinvarr[r] = sinv;
    }
}

// ---------------- K2b: fp64 refinement of band candidates + exact final select --
__global__ __launch_bounds__(256) void refine_select(
    const float* __restrict__ X, const float* __restrict__ Wenc,
    const float* __restrict__ benc, const float* __restrict__ gamma,
    const float* __restrict__ beta, const int* __restrict__ band_idx,
    const int* __restrict__ cdef, const int* __restrict__ nband,
    const float* __restrict__ muarr, const float* __restrict__ sinvarr,
    int* __restrict__ sel_idx, float* __restrict__ sel_val,
    float* __restrict__ feat)
{
    __shared__ float xs[DIM];
    __shared__ float cval[BAND_CAP];
    __shared__ int   cidx[BAND_CAP];
    __shared__ int   scnt;
    const int t = threadIdx.x;
    const long r = blockIdx.x;
    const int w = t >> 6, l = t & 63;

    for (int i = t; i < DIM; i += 256) xs[i] = X[r * DIM + i];
    if (t == 0) scnt = 0;
    const int nb = nband[r];
    const int cd = cdef[r];
    int need = TOPK - cd; if (need > nb) need = nb;
    const double mu = (double)muarr[r], sinv = (double)sinvarr[r];
    __syncthreads();

    for (int c = w; c < nb; c += 4) {
        const int fi = band_idx[r * BAND_CAP + c];
        const float* wr = Wenc + (size_t)fi * DIM;
        double s = 0.0;
        for (int k = l; k < DIM; k += 64) s = fma((double)xs[k], (double)wr[k], s);
#pragma unroll
        for (int o = 32; o > 0; o >>= 1) s += __shfl_down(s, o, 64);
        if (l == 0) {
            const double z = s + (double)benc[fi];
            const double a = (z - mu) * sinv * (double)gamma[fi] + (double)beta[fi];
            cval[c] = fmaxf((float)a, 0.f);
            cidx[c] = fi;
        }
    }
    __syncthreads();
    if (t < nb) {
        const float v = cval[t];
        const int id = cidx[t];
        int rank = 0;
        for (int j = 0; j < nb; ++j) {
            const float vj = cval[j];
            rank += (vj > v) || (vj == v && cidx[j] < id);
        }
        if (rank < need) {
            const int s = atomicAdd(&scnt, 1);
            sel_idx[r * TOPK + cd + s] = id;
            sel_val[r * TOPK + cd + s] = v;
            if (feat) feat[r * (size_t)FDICT + id] = v;
        }
    }
}

// ---------------- K3: transpose W_dec [768][32768] -> WdTb [32768][768] bf16 ----
__global__ __launch_bounds__(256) void transposeWd(
    const float* __restrict__ Wd, unsigned short* __restrict__ WdTb)
{
    __shared__ float tile[32][33];
    const int fx = blockIdx.x * 32;
    const int dy = blockIdx.y * 32;
    const int tx = threadIdx.x & 31;
    const int ty = threadIdx.x >> 5;
    for (int i = ty; i < 32; i += 8)
        tile[i][tx] = Wd[(size_t)(dy + i) * FDICT + fx + tx];
    __syncthreads();
    for (int i = ty; i < 32; i += 8)
        WdTb[(size_t)(fx + i) * DIM + dy + tx] = (unsigned short)f2bf(tile[tx][i]);
}

// ---------------- K4: sparse decode (bf16 W_decT, fp32 math) --------------------
__global__ __launch_bounds__(384) void decode(
    const int* __restrict__ sel_idx, const float* __restrict__ sel_val,
    const unsigned short* __restrict__ WdTb, const float* __restrict__ bdec,
    float* __restrict__ out)
{
    __shared__ int   sidx[TOPK];
    __shared__ float sval[TOPK];
    const int t = threadIdx.x;
    const long r = blockIdx.x;
    if (t < TOPK) { sidx[t] = sel_idx[r * TOPK + t]; sval[t] = sel_val[r * TOPK + t]; }
    __syncthreads();
    const float2 b2 = *(const float2*)(bdec + t * 2);
    float a0 = b2.x, a1 = b2.y;
    for (int j = 0; j < TOPK; ++j) {
        const unsigned wp = *(const unsigned*)(WdTb + (size_t)sidx[j] * DIM + t * 2);
        const float v = sval[j];
        a0 = fmaf(v, __uint_as_float((wp & 0xFFFFu) << 16), a0);
        a1 = fmaf(v, __uint_as_float(wp & 0xFFFF0000u), a1);
    }
    float2 o2; o2.x = a0; o2.y = a1;
    *(float2*)(out + r * DIM + t * 2) = o2;
}

// ---------------- K5 (fallback only): zero rows + scatter -----------------------
__global__ __launch_bounds__(1024) void featfill(
    const int* __restrict__ sel_idx, const float* __restrict__ sel_val,
    float* __restrict__ feat)
{
    const int t = threadIdx.x;
    const long r = blockIdx.x;
    const f32x4 z4 = (f32x4){0.f, 0.f, 0.f, 0.f};
    f32x4* row4 = (f32x4*)(feat + r * FDICT);
    for (int i = t; i < FDICT / 4; i += 1024)
        __builtin_nontemporal_store(z4, &row4[i]);
    __syncthreads();
    if (t < TOPK)
        feat[r * FDICT + sel_idx[r * TOPK + t]] = sel_val[r * TOPK + t];
}

extern "C" void kernel_launch(void* const* d_in, const int* in_sizes, int n_in,
                              void* d_out, int out_size, void* d_ws, size_t ws_size,
                              hipStream_t stream)
{
    const float* x     = (const float*)d_in[0];
    const float* Wenc  = (const float*)d_in[1];
    const float* benc  = (const float*)d_in[2];
    const float* gamma = (const float*)d_in[3];
    const float* beta  = (const float*)d_in[4];
    const float* Wdec  = (const float*)d_in[5];
    const float* bdec  = (const float*)d_in[6];

    float* out  = (float*)d_out;                      // [8192*768] fp32
    float* feat = out + (size_t)R_TOT * DIM;          // [8192*32768] fp32 region

    unsigned short* Xb = (unsigned short*)out;        // 12.6 MB (dead until decode)

    char* ws = (char*)d_ws;
    int*   sidx  = (int*)ws;                                        // 4 MB
    float* sval  = (float*)(ws + (size_t)R_TOT * TOPK * 4);         // 4 MB
    int*   bidx  = (int*)(ws + (size_t)R_TOT * TOPK * 8);           // 6.3 MB
    int*   cdef  = (int*)(ws + (size_t)R_TOT * (TOPK * 8 + BAND_CAP * 4));
    int*   nbnd  = cdef + R_TOT;
    float* muarr = (float*)(nbnd + R_TOT);
    float* sinva = muarr + R_TOT;

    // big-workspace path: Zb/Wb/WdTb live in ws -> feat region free during topk
    const size_t WS_NEED = 624ull << 20;   // 16 MiB small + 512 + 48 + 48 MiB
    const bool big = (ws_size >= WS_NEED);

    unsigned short* Zb, *Wb, *WdTb;
    if (big) {
        Zb   = (unsigned short*)(ws + (16ull << 20));
        Wb   = (unsigned short*)(ws + (528ull << 20));
        WdTb = (unsigned short*)(ws + (576ull << 20));
    } else {
        Zb   = (unsigned short*)feat;                            // 537 MB
        Wb   = (unsigned short*)((char*)feat + 536870912ull);    // 50.3 MB
        WdTb = (unsigned short*)((char*)feat + 587202560ull);    // 50.3 MB
    }
    float* featArg = big ? feat : nullptr;

    conv_bf16<<<1536, 256, 0, stream>>>(x,    Xb, R_TOT * DIM / 8);
    conv_bf16<<<2048, 256, 0, stream>>>(Wenc, Wb, FDICT * DIM / 8);
    enc_gemm<<<4096, 512, 0, stream>>>(Xb, Wb, benc, Zb);
    topk_select<<<R_TOT, 1024, 0, stream>>>(Zb, gamma, beta, sidx, sval,
                                            bidx, cdef, nbnd, muarr, sinva,
                                            featArg);
    refine_select<<<R_TOT, 256, 0, stream>>>(x, Wenc, benc, gamma, beta,
                                             bidx, cdef, nbnd, muarr, sinva,
                                             sidx, sval, featArg);
    transposeWd<<<dim3(FDICT / 32, DIM / 32), 256, 0, stream>>>(Wdec, WdTb);
    decode<<<R_TOT, 384, 0, stream>>>(sidx, sval, WdTb, bdec, out);
    if (!big)
        featfill<<<R_TOT, 1024, 0, stream>>>(sidx, sval, feat);
}